// Round 10
// baseline (11359.364 us; speedup 1.0000x reference)
//
#include <hip/hip_runtime.h>
#include <hip/hip_bf16.h>

#define NTOT  65536
#define NE    524288
#define NG    64
#define NPG   1024
#define EMB   128
#define STEPS 4

// d_out is a 4-byte-per-element buffer (f32-sized slots, 328064 slots).
// The harness's bf16 comparator reads the bf16 bit-pattern from the u16
// halves of each slot: flat[j] = u16[2j(+phi)]. Write BOTH halves.
// Flat index layout: a_probs j=g*5+o | node_sm j=320+5n+o | value j=328000+g.
typedef unsigned short u16;
typedef unsigned int   u32;

__device__ __forceinline__ float lrelu(float v){ return v > 0.f ? v : 0.01f*v; }
__device__ __forceinline__ u16 f2bf(float f){
    u32 u = __float_as_uint(f);
    u32 r = (u + 0x7FFFu + ((u>>16)&1u)) >> 16;   // round-to-nearest-even
    return (u16)r;
}
__device__ __forceinline__ void store_out(u32* out, int j, float v){
    u32 b = (u32)f2bf(v);
    out[j] = (b << 16) | b;      // bf16 bits in both u16 halves of slot j
}

// ---------------- embed: x = lrelu(nf @ W + b) ----------------
__global__ __launch_bounds__(256) void k_embed(const float* __restrict__ nf,
                        const float* __restrict__ W,
                        const float* __restrict__ b, float* __restrict__ x) {
    int idx = blockIdx.x*256 + threadIdx.x;      // n*128 + c
    int n = idx >> 7, c = idx & 127;
    const float* f = nf + n*5;
    float acc = b[c];
    #pragma unroll
    for (int k=0;k<5;k++) acc += f[k]*W[k*EMB+c];
    x[idx] = lrelu(acc);
}

// ---------------- message + scatter-max ----------------
// block: 256 threads = 16 edges x 16 colgroups(8 cols)
__global__ __launch_bounds__(256) void k_message(const float* __restrict__ x,
                          const float* __restrict__ ea,
                          const int* __restrict__ srcv, const int* __restrict__ dstv,
                          const float* __restrict__ W, const float* __restrict__ b,
                          u32* __restrict__ agg) {
    __shared__ float in[16][132];
    int e0 = blockIdx.x*16;
    int t = threadIdx.x;
    for (int i=t;i<16*132;i+=256){
        int le = i/132, k = i - le*132;
        int e = e0+le;
        in[le][k] = (k<128) ? x[(size_t)srcv[e]*EMB + k] : ea[(size_t)e*4 + (k-128)];
    }
    __syncthreads();
    int le = t>>4, c = (t&15)*8;
    int e = e0+le;
    float acc[8];
    #pragma unroll
    for (int j=0;j<8;j++) acc[j] = b[c+j];
    for (int k=0;k<132;k++){
        float v = in[le][k];
        const float4 w0 = *(const float4*)(W + (size_t)k*EMB + c);
        const float4 w1 = *(const float4*)(W + (size_t)k*EMB + c + 4);
        acc[0]+=v*w0.x; acc[1]+=v*w0.y; acc[2]+=v*w0.z; acc[3]+=v*w0.w;
        acc[4]+=v*w1.x; acc[5]+=v*w1.y; acc[6]+=v*w1.z; acc[7]+=v*w1.w;
    }
    int d = dstv[e];
    u32* p = agg + (size_t)d*EMB + c;
    #pragma unroll
    for (int j=0;j<8;j++){
        float v = lrelu(acc[j]);
        if (v >= 0.f) atomicMax((int*)(p+j), __float_as_int(v));
        else          atomicMin(p+j, __float_as_uint(v));
    }
}

// ---------------- x = lrelu([x, xg[b], agg] @ W + b) + x ----------------
// block: 256 = 8 nodes x 32 colgroups(4 cols)
__global__ __launch_bounds__(256) void k_aggupd(float* __restrict__ x,
                         const float* __restrict__ xg,
                         const u32* __restrict__ agg,
                         const float* __restrict__ W, const float* __restrict__ b) {
    __shared__ float in[8][384];
    int n0 = blockIdx.x*8;
    int t = threadIdx.x;
    for (int i=t;i<8*384;i+=256){
        int ln = i/384, k = i - ln*384;
        int n = n0+ln;
        float v;
        if (k<128)       v = x[(size_t)n*EMB+k];
        else if (k<256)  v = xg[(n>>10)*EMB + (k-128)];
        else {
            u32 u = agg[(size_t)n*EMB + (k-256)];
            v = __uint_as_float(u);
            if (((u>>23)&0xFFu)==0xFFu) v = 0.f;   // -inf / NaN (untouched) -> 0
        }
        in[ln][k]=v;
    }
    __syncthreads();
    int ln=t>>5, c=(t&31)*4, n=n0+ln;
    float4 acc = make_float4(b[c],b[c+1],b[c+2],b[c+3]);
    for (int k=0;k<384;k++){
        float v = in[ln][k];
        const float4 w4 = *(const float4*)(W + (size_t)k*EMB + c);
        acc.x += v*w4.x; acc.y += v*w4.y; acc.z += v*w4.z; acc.w += v*w4.w;
    }
    float* xp = x + (size_t)n*EMB + c;
    xp[0] = lrelu(acc.x) + in[ln][c];
    xp[1] = lrelu(acc.y) + in[ln][c+1];
    xp[2] = lrelu(acc.z) + in[ln][c+2];
    xp[3] = lrelu(acc.w) + in[ln][c+3];
}

// ---------------- gate + per-graph softmax weights ----------------
__global__ __launch_bounds__(256) void k_gatepool(const float* __restrict__ x,
                           const float* __restrict__ gw,
                           const float* __restrict__ gb, float* __restrict__ w,
                           float* __restrict__ xgn) {
    __shared__ float red[4];
    __shared__ float bmax, bsum;
    int g = blockIdx.x, t = threadIdx.x;
    if (t < EMB) xgn[g*EMB + t] = 0.f;       // zero xg_new for this step
    float gv[4];
    #pragma unroll
    for (int j=0;j<4;j++){
        int n = g*NPG + j*256 + t;
        const float4* xr = (const float4*)(x + (size_t)n*EMB);
        float acc = 0.f;
        for (int k=0;k<EMB/4;k++){
            float4 v = xr[k];
            float4 gw4 = ((const float4*)gw)[k];
            acc += v.x*gw4.x + v.y*gw4.y + v.z*gw4.z + v.w*gw4.w;
        }
        gv[j] = acc + gb[0];
    }
    float m = fmaxf(fmaxf(gv[0],gv[1]),fmaxf(gv[2],gv[3]));
    #pragma unroll
    for (int o=1;o<64;o<<=1) m = fmaxf(m, __shfl_xor(m, o));
    int wv = t>>6;
    if ((t&63)==0) red[wv] = m;
    __syncthreads();
    if (t==0) bmax = fmaxf(fmaxf(red[0],red[1]), fmaxf(red[2],red[3]));
    __syncthreads();
    m = bmax;
    float e[4]; float s = 0.f;
    #pragma unroll
    for (int j=0;j<4;j++){ e[j] = expf(gv[j]-m); s += e[j]; }
    #pragma unroll
    for (int o=1;o<64;o<<=1) s += __shfl_xor(s, o);
    __syncthreads();
    if ((t&63)==0) red[wv] = s;
    __syncthreads();
    if (t==0) bsum = red[0]+red[1]+red[2]+red[3];
    __syncthreads();
    float inv = 1.f/bsum;
    #pragma unroll
    for (int j=0;j<4;j++){
        int n = g*NPG + j*256 + t;
        w[n] = e[j]*inv;
    }
}

// ---------------- feat = lrelu(x @ fW + fb); xg_new += w[n]*feat ----------------
// grid: G * 8 nodechunks * 2 colhalves; block 256 = 4 nodes x 64 cols
__global__ __launch_bounds__(256) void k_featpool(const float* __restrict__ x,
                           const float* __restrict__ w,
                           const float* __restrict__ W, const float* __restrict__ b,
                           float* __restrict__ xgn) {
    __shared__ float Wh[EMB][64];
    __shared__ float xr[4][EMB];
    __shared__ float red[4][64];
    int bid = blockIdx.x;
    int ch = bid & 1, chunk = (bid>>1)&7, g = bid>>4;
    int c0 = ch*64;
    int t = threadIdx.x;
    for (int i=t;i<EMB*64;i+=256){
        int k=i>>6, c=i&63;
        Wh[k][c] = W[(size_t)k*EMB + c0 + c];
    }
    int tn = t>>6, tc = t&63;
    float bias = b[c0+tc];
    float sum = 0.f;
    int nbase = g*NPG + chunk*128;
    for (int it=0; it<32; ++it){
        __syncthreads();
        for (int i=t;i<4*EMB;i+=256){
            int ln=i>>7, k=i&127;
            xr[ln][k] = x[(size_t)(nbase + it*4 + ln)*EMB + k];
        }
        __syncthreads();
        float acc = bias;
        #pragma unroll 16
        for (int k=0;k<EMB;k++) acc += xr[tn][k]*Wh[k][tc];
        int n = nbase + it*4 + tn;
        sum += w[n]*lrelu(acc);
    }
    red[tn][tc] = sum;
    __syncthreads();
    if (t<64){
        float s = red[0][t]+red[1][t]+red[2][t]+red[3][t];
        atomicAdd(&xgn[g*EMB + c0 + t], s);
    }
}

// ---------------- xg = lrelu([xg_new, xg] @ W + b) + xg ----------------
__global__ __launch_bounds__(128) void k_tr(float* __restrict__ xg,
                     const float* __restrict__ xgn,
                     const float* __restrict__ W, const float* __restrict__ b) {
    __shared__ float in[256];
    int g = blockIdx.x, t = threadIdx.x;   // 128 threads
    in[t]     = xgn[g*EMB + t];
    in[128+t] = xg[g*EMB + t];
    __syncthreads();
    float acc = b[t];
    for (int k=0;k<256;k++) acc += in[k]*W[(size_t)k*EMB + t];
    xg[g*EMB+t] = lrelu(acc) + in[128+t];
}

// ---------------- graph heads: a_probs + value ----------------
__global__ __launch_bounds__(64) void k_ghead(const float* __restrict__ xg,
                        const float* __restrict__ actW, const float* __restrict__ actb,
                        const float* __restrict__ valW, const float* __restrict__ valb,
                        u32* __restrict__ out) {
    int g = blockIdx.x, l = threadIdx.x;   // 64 threads
    float xa = xg[g*EMB + l], xb = xg[g*EMB + 64 + l];
    float acc[6];
    #pragma unroll
    for (int o=0;o<5;o++) acc[o] = xa*actW[l*5+o] + xb*actW[(l+64)*5+o];
    acc[5] = xa*valW[l] + xb*valW[64+l];
    #pragma unroll
    for (int o=0;o<6;o++){
        float sv = acc[o];
        #pragma unroll
        for (int d=1;d<64;d<<=1) sv += __shfl_xor(sv, d);
        acc[o] = sv;
    }
    if (l==0){
        float lg[5], m = -1e30f;
        #pragma unroll
        for (int o=0;o<5;o++){ lg[o]=acc[o]+actb[o]; m = fmaxf(m, lg[o]); }
        float ssum=0.f;
        #pragma unroll
        for (int o=0;o<5;o++){ lg[o]=expf(lg[o]-m); ssum+=lg[o]; }
        float inv = 1.f/ssum;
        #pragma unroll
        for (int o=0;o<5;o++) store_out(out, g*5+o, lg[o]*inv);
        store_out(out, 328000 + g, acc[5] + valb[0]);
    }
}

// ---------------- node logits ----------------
__global__ __launch_bounds__(256) void k_nlog(const float* __restrict__ x,
                       const float* __restrict__ W,
                       const float* __restrict__ b, float* __restrict__ nl) {
    int n = blockIdx.x*256 + threadIdx.x;
    const float4* xr = (const float4*)(x + (size_t)n*EMB);
    float acc[5] = {b[0],b[1],b[2],b[3],b[4]};
    for (int k=0;k<32;k++){
        float4 v4 = xr[k];
        #pragma unroll
        for (int jj=0;jj<4;jj++){
            float v = (&v4.x)[jj];
            int k4 = k*4+jj;
            #pragma unroll
            for (int o=0;o<5;o++) acc[o] += v*W[k4*5+o];
        }
    }
    #pragma unroll
    for (int o=0;o<5;o++) nl[(size_t)n*5+o] = acc[o];
}

// ---------------- per-graph per-channel softmax over nodes ----------------
__global__ __launch_bounds__(256) void k_nodesm(const float* __restrict__ nl,
                         u32* __restrict__ out) {
    __shared__ float red[5][4];
    int g = blockIdx.x, t = threadIdx.x;
    float v[4][5];
    #pragma unroll
    for (int it=0; it<4; ++it){
        int n = g*NPG + it*256 + t;
        #pragma unroll
        for (int o=0;o<5;o++) v[it][o] = nl[(size_t)n*5+o];
    }
    float m[5];
    #pragma unroll
    for (int o=0;o<5;o++){
        float mm = fmaxf(fmaxf(v[0][o],v[1][o]),fmaxf(v[2][o],v[3][o]));
        #pragma unroll
        for (int d=1;d<64;d<<=1) mm = fmaxf(mm, __shfl_xor(mm,d));
        if ((t&63)==0) red[o][t>>6] = mm;
    }
    __syncthreads();
    #pragma unroll
    for (int o=0;o<5;o++)
        m[o] = fmaxf(fmaxf(red[o][0],red[o][1]),fmaxf(red[o][2],red[o][3]));
    __syncthreads();
    #pragma unroll
    for (int o=0;o<5;o++){
        float ss = 0.f;
        #pragma unroll
        for (int it=0;it<4;it++){ v[it][o] = expf(v[it][o]-m[o]); ss += v[it][o]; }
        #pragma unroll
        for (int d=1;d<64;d<<=1) ss += __shfl_xor(ss,d);
        if ((t&63)==0) red[o][t>>6] = ss;
    }
    __syncthreads();
    float s[5];
    #pragma unroll
    for (int o=0;o<5;o++)
        s[o] = 1.f/(red[o][0]+red[o][1]+red[o][2]+red[o][3]);
    #pragma unroll
    for (int it=0;it<4;it++){
        int n = g*NPG + it*256 + t;
        #pragma unroll
        for (int o=0;o<5;o++)
            store_out(out, 320 + n*5 + o, v[it][o]*s[o]);
    }
}

extern "C" void kernel_launch(void* const* d_in, const int* in_sizes, int n_in,
                              void* d_out, int out_size, void* d_ws, size_t ws_size,
                              hipStream_t stream) {
    const float* node_feats = (const float*)d_in[0];
    const float* edge_attr  = (const float*)d_in[1];
    const int*   edge_index = (const int*)d_in[2];
    const float* embed_W = (const float*)d_in[4];
    const float* embed_b = (const float*)d_in[5];
    const float* mess_W  = (const float*)d_in[6];
    const float* mess_b  = (const float*)d_in[7];
    const float* agg_W   = (const float*)d_in[8];
    const float* agg_b   = (const float*)d_in[9];
    const float* gate_W  = (const float*)d_in[10];
    const float* gate_b  = (const float*)d_in[11];
    const float* feat_W  = (const float*)d_in[12];
    const float* feat_b  = (const float*)d_in[13];
    const float* tr_W    = (const float*)d_in[14];
    const float* tr_b    = (const float*)d_in[15];
    const float* node_W  = (const float*)d_in[16];
    const float* node_b  = (const float*)d_in[17];
    const float* act_W   = (const float*)d_in[18];
    const float* act_b   = (const float*)d_in[19];
    const float* val_W   = (const float*)d_in[20];
    const float* val_b   = (const float*)d_in[21];

    // Workspace (64 MiB):
    //   x   f32 [0, 32MB)          persistent node features
    //   agg u32 [32MB, 64MB)       per-step scatter-max (dead after aggupd)
    //   w   = agg+0      (256KB)   alive gatepool->featpool
    //   xgn = agg+256KB  (32KB)    alive gatepool->tr
    //   nl  = agg+0      (1.25MB)  alive only after MP loop
    // xg (32KB) stashed at d_out bytes [4096, 36864) -- inside node_sm's
    // slot region (bytes [1280, 1312000)), overwritten by k_nodesm at the
    // very end, after k_ghead's final read.
    char* ws = (char*)d_ws;
    float* x   = (float*)(ws);
    u32*   agg = (u32*)(ws + 33554432);
    float* w   = (float*)(ws + 33554432);
    float* xgn = (float*)(ws + 33554432 + 262144);
    float* nl  = (float*)(ws + 33554432);
    u32* out = (u32*)d_out;
    float* xg  = (float*)((char*)d_out + 4096);

    const int* srcv = edge_index;
    const int* dstv = edge_index + NE;

    hipMemsetAsync(xg, 0, NG*EMB*sizeof(float), stream);
    k_embed<<<NTOT*EMB/256, 256, 0, stream>>>(node_feats, embed_W, embed_b, x);

    for (int i=0;i<STEPS;i++){
        hipMemsetAsync(agg, 0xFF, (size_t)NTOT*EMB*4, stream);
        k_message<<<NE/16, 256, 0, stream>>>(x, edge_attr, srcv, dstv,
            mess_W + (size_t)i*132*EMB, mess_b + i*EMB, agg);
        k_aggupd<<<NTOT/8, 256, 0, stream>>>(x, xg, agg,
            agg_W + (size_t)i*384*EMB, agg_b + i*EMB);
        k_gatepool<<<NG, 256, 0, stream>>>(x, gate_W + i*EMB, gate_b + i, w, xgn);
        k_featpool<<<NG*16, 256, 0, stream>>>(x, w,
            feat_W + (size_t)i*EMB*EMB, feat_b + i*EMB, xgn);
        k_tr<<<NG, 128, 0, stream>>>(xg, xgn, tr_W + (size_t)i*256*EMB, tr_b + i*EMB);
    }

    k_ghead<<<NG, 64, 0, stream>>>(xg, act_W, act_b, val_W, val_b, out);
    k_nlog<<<NTOT/256, 256, 0, stream>>>(x, node_W, node_b, nl);
    k_nodesm<<<NG, 256, 0, stream>>>(nl, out);
}

// Round 11
// 6633.199 us; speedup vs baseline: 1.7125x; 1.7125x over previous
//
#include <hip/hip_runtime.h>
#include <hip/hip_bf16.h>

#define NTOT  65536
#define NE    524288
#define NG    64
#define NPG   1024
#define EMB   128
#define STEPS 4

typedef unsigned short u16;
typedef unsigned int   u32;

__device__ __forceinline__ float lrelu(float v){ return v > 0.f ? v : 0.01f*v; }
__device__ __forceinline__ u16 f2bf(float f){
    u32 u = __float_as_uint(f);
    u32 r = (u + 0x7FFFu + ((u>>16)&1u)) >> 16;   // round-to-nearest-even
    return (u16)r;
}
__device__ __forceinline__ void store_out(u32* out, int j, float v){
    u32 b = (u32)f2bf(v);
    out[j] = (b << 16) | b;      // bf16 bits in both u16 halves of slot j
}

// ================= CSR build (once per launch) =================
__global__ __launch_bounds__(256) void k_count(const int* __restrict__ dstv,
                                               u32* __restrict__ cnt){
    int e = blockIdx.x*256 + threadIdx.x;
    atomicAdd(&cnt[dstv[e]], 1u);
}

__global__ __launch_bounds__(1024) void k_scan(const u32* __restrict__ cnt,
                                               u32* __restrict__ off,
                                               u32* __restrict__ cursor){
    __shared__ u32 part[1024];
    int t = threadIdx.x;
    u32 s = 0;
    for (int i=0;i<64;i++) s += cnt[t*64+i];
    part[t] = s; __syncthreads();
    for (int d=1; d<1024; d<<=1){
        u32 v = (t>=d) ? part[t-d] : 0u;
        __syncthreads();
        part[t] += v;
        __syncthreads();
    }
    u32 base = (t==0) ? 0u : part[t-1];
    for (int i=0;i<64;i++){
        off[t*64+i] = base; cursor[t*64+i] = base;
        base += cnt[t*64+i];
    }
    if (t==1023) off[65536] = base;
}

__global__ __launch_bounds__(256) void k_scatter(const int* __restrict__ dstv,
                                                 u32* __restrict__ cursor,
                                                 u32* __restrict__ perm){
    int e = blockIdx.x*256 + threadIdx.x;
    u32 pos = atomicAdd(&cursor[dstv[e]], 1u);
    perm[pos] = e;
}

// ---------------- embed: x = lrelu(nf @ W + b) ----------------
__global__ __launch_bounds__(256) void k_embed(const float* __restrict__ nf,
                        const float* __restrict__ W,
                        const float* __restrict__ b, float* __restrict__ x) {
    int idx = blockIdx.x*256 + threadIdx.x;
    int n = idx >> 7, c = idx & 127;
    const float* f = nf + n*5;
    float acc = b[c];
    #pragma unroll
    for (int k=0;k<5;k++) acc += f[k]*W[k*EMB+c];
    x[idx] = lrelu(acc);
}

// ---------------- message GEMM + gather-max (no atomics) ----------------
// block: 256 threads; owns 16 dst nodes; edges pre-sorted by dst via perm.
__global__ __launch_bounds__(256) void k_msgmax(const float* __restrict__ x,
                          const float* __restrict__ ea,
                          const int* __restrict__ srcv, const int* __restrict__ dstv,
                          const u32* __restrict__ off, const u32* __restrict__ perm,
                          const float* __restrict__ W, const float* __restrict__ b,
                          float* __restrict__ agg) {
    __shared__ float in[16][132];
    __shared__ float sc[16][128];
    __shared__ int   ldst[16];
    int n0 = blockIdx.x*16;
    int t = threadIdx.x;
    u32 j0 = off[n0], j1 = off[n0+16];
    int le = t>>4, c = (t&15)*8;
    float bias[8], racc[8];
    #pragma unroll
    for (int q=0;q<8;q++){ bias[q] = b[c+q]; racc[q] = -INFINITY; }

    for (u32 j=j0; j<j1; j+=16){
        for (int i=t;i<16*132;i+=256){
            int l = i/132, k = i - l*132;
            u32 jj = j + l;
            float v = 0.f;
            if (jj < j1){
                u32 e = perm[jj];
                v = (k<128) ? x[(size_t)srcv[e]*EMB + k] : ea[(size_t)e*4 + (k-128)];
            }
            in[l][k] = v;
        }
        if (t<16){ u32 jj = j+t; ldst[t] = (jj<j1) ? (dstv[perm[jj]] - n0) : -1; }
        __syncthreads();
        float acc[8];
        #pragma unroll
        for (int q=0;q<8;q++) acc[q] = bias[q];
        for (int k=0;k<132;k++){
            float v = in[le][k];
            const float4 w0 = *(const float4*)(W + (size_t)k*EMB + c);
            const float4 w1 = *(const float4*)(W + (size_t)k*EMB + c + 4);
            acc[0]+=v*w0.x; acc[1]+=v*w0.y; acc[2]+=v*w0.z; acc[3]+=v*w0.w;
            acc[4]+=v*w1.x; acc[5]+=v*w1.y; acc[6]+=v*w1.z; acc[7]+=v*w1.w;
        }
        #pragma unroll
        for (int q=0;q<8;q++) sc[le][c+q] = lrelu(acc[q]);
        __syncthreads();
        #pragma unroll
        for (int l2=0;l2<16;l2++){
            if (ldst[l2] == le){
                #pragma unroll
                for (int q=0;q<8;q++) racc[q] = fmaxf(racc[q], sc[l2][c+q]);
            }
        }
        __syncthreads();
    }
    #pragma unroll
    for (int q=0;q<8;q++){
        float v = racc[q];
        agg[(size_t)(n0+le)*EMB + c + q] = (v == -INFINITY) ? 0.f : v;
    }
}

// ---------------- x = lrelu([x, xg[b], agg] @ W + b) + x ----------------
__global__ __launch_bounds__(256) void k_aggupd(float* __restrict__ x,
                         const float* __restrict__ xg,
                         const float* __restrict__ agg,
                         const float* __restrict__ W, const float* __restrict__ b) {
    __shared__ float in[8][384];
    int n0 = blockIdx.x*8;
    int t = threadIdx.x;
    for (int i=t;i<8*384;i+=256){
        int ln = i/384, k = i - ln*384;
        int n = n0+ln;
        float v;
        if (k<128)       v = x[(size_t)n*EMB+k];
        else if (k<256)  v = xg[(n>>10)*EMB + (k-128)];
        else             v = agg[(size_t)n*EMB + (k-256)];
        in[ln][k]=v;
    }
    __syncthreads();
    int ln=t>>5, c=(t&31)*4, n=n0+ln;
    float4 acc = make_float4(b[c],b[c+1],b[c+2],b[c+3]);
    for (int k=0;k<384;k++){
        float v = in[ln][k];
        const float4 w4 = *(const float4*)(W + (size_t)k*EMB + c);
        acc.x += v*w4.x; acc.y += v*w4.y; acc.z += v*w4.z; acc.w += v*w4.w;
    }
    float* xp = x + (size_t)n*EMB + c;
    xp[0] = lrelu(acc.x) + in[ln][c];
    xp[1] = lrelu(acc.y) + in[ln][c+1];
    xp[2] = lrelu(acc.z) + in[ln][c+2];
    xp[3] = lrelu(acc.w) + in[ln][c+3];
}

// ---------------- gate + per-graph softmax weights ----------------
__global__ __launch_bounds__(256) void k_gatepool(const float* __restrict__ x,
                           const float* __restrict__ gw,
                           const float* __restrict__ gb, float* __restrict__ w,
                           float* __restrict__ xgn) {
    __shared__ float red[4];
    __shared__ float bmax, bsum;
    int g = blockIdx.x, t = threadIdx.x;
    if (t < EMB) xgn[g*EMB + t] = 0.f;
    float gv[4];
    #pragma unroll
    for (int j=0;j<4;j++){
        int n = g*NPG + j*256 + t;
        const float4* xr = (const float4*)(x + (size_t)n*EMB);
        float acc = 0.f;
        for (int k=0;k<EMB/4;k++){
            float4 v = xr[k];
            float4 gw4 = ((const float4*)gw)[k];
            acc += v.x*gw4.x + v.y*gw4.y + v.z*gw4.z + v.w*gw4.w;
        }
        gv[j] = acc + gb[0];
    }
    float m = fmaxf(fmaxf(gv[0],gv[1]),fmaxf(gv[2],gv[3]));
    #pragma unroll
    for (int o=1;o<64;o<<=1) m = fmaxf(m, __shfl_xor(m, o));
    int wv = t>>6;
    if ((t&63)==0) red[wv] = m;
    __syncthreads();
    if (t==0) bmax = fmaxf(fmaxf(red[0],red[1]), fmaxf(red[2],red[3]));
    __syncthreads();
    m = bmax;
    float e[4]; float s = 0.f;
    #pragma unroll
    for (int j=0;j<4;j++){ e[j] = expf(gv[j]-m); s += e[j]; }
    #pragma unroll
    for (int o=1;o<64;o<<=1) s += __shfl_xor(s, o);
    __syncthreads();
    if ((t&63)==0) red[wv] = s;
    __syncthreads();
    if (t==0) bsum = red[0]+red[1]+red[2]+red[3];
    __syncthreads();
    float inv = 1.f/bsum;
    #pragma unroll
    for (int j=0;j<4;j++){
        int n = g*NPG + j*256 + t;
        w[n] = e[j]*inv;
    }
}

// ---------------- feat = lrelu(x @ fW + fb); xg_new += w[n]*feat ----------------
__global__ __launch_bounds__(256) void k_featpool(const float* __restrict__ x,
                           const float* __restrict__ w,
                           const float* __restrict__ W, const float* __restrict__ b,
                           float* __restrict__ xgn) {
    __shared__ float Wh[EMB][64];
    __shared__ float xr[4][EMB];
    __shared__ float red[4][64];
    int bid = blockIdx.x;
    int ch = bid & 1, chunk = (bid>>1)&7, g = bid>>4;
    int c0 = ch*64;
    int t = threadIdx.x;
    for (int i=t;i<EMB*64;i+=256){
        int k=i>>6, c=i&63;
        Wh[k][c] = W[(size_t)k*EMB + c0 + c];
    }
    int tn = t>>6, tc = t&63;
    float bias = b[c0+tc];
    float sum = 0.f;
    int nbase = g*NPG + chunk*128;
    for (int it=0; it<32; ++it){
        __syncthreads();
        for (int i=t;i<4*EMB;i+=256){
            int ln=i>>7, k=i&127;
            xr[ln][k] = x[(size_t)(nbase + it*4 + ln)*EMB + k];
        }
        __syncthreads();
        float acc = bias;
        #pragma unroll 16
        for (int k=0;k<EMB;k++) acc += xr[tn][k]*Wh[k][tc];
        int n = nbase + it*4 + tn;
        sum += w[n]*lrelu(acc);
    }
    red[tn][tc] = sum;
    __syncthreads();
    if (t<64){
        float s = red[0][t]+red[1][t]+red[2][t]+red[3][t];
        atomicAdd(&xgn[g*EMB + c0 + t], s);
    }
}

// ---------------- xg = lrelu([xg_new, xg] @ W + b) + xg ----------------
__global__ __launch_bounds__(128) void k_tr(float* __restrict__ xg,
                     const float* __restrict__ xgn,
                     const float* __restrict__ W, const float* __restrict__ b) {
    __shared__ float in[256];
    int g = blockIdx.x, t = threadIdx.x;
    in[t]     = xgn[g*EMB + t];
    in[128+t] = xg[g*EMB + t];
    __syncthreads();
    float acc = b[t];
    for (int k=0;k<256;k++) acc += in[k]*W[(size_t)k*EMB + t];
    xg[g*EMB+t] = lrelu(acc) + in[128+t];
}

// ---------------- graph heads: a_probs + value ----------------
__global__ __launch_bounds__(64) void k_ghead(const float* __restrict__ xg,
                        const float* __restrict__ actW, const float* __restrict__ actb,
                        const float* __restrict__ valW, const float* __restrict__ valb,
                        u32* __restrict__ out) {
    int g = blockIdx.x, l = threadIdx.x;
    float xa = xg[g*EMB + l], xb = xg[g*EMB + 64 + l];
    float acc[6];
    #pragma unroll
    for (int o=0;o<5;o++) acc[o] = xa*actW[l*5+o] + xb*actW[(l+64)*5+o];
    acc[5] = xa*valW[l] + xb*valW[64+l];
    #pragma unroll
    for (int o=0;o<6;o++){
        float sv = acc[o];
        #pragma unroll
        for (int d=1;d<64;d<<=1) sv += __shfl_xor(sv, d);
        acc[o] = sv;
    }
    if (l==0){
        float lg[5], m = -1e30f;
        #pragma unroll
        for (int o=0;o<5;o++){ lg[o]=acc[o]+actb[o]; m = fmaxf(m, lg[o]); }
        float ssum=0.f;
        #pragma unroll
        for (int o=0;o<5;o++){ lg[o]=expf(lg[o]-m); ssum+=lg[o]; }
        float inv = 1.f/ssum;
        #pragma unroll
        for (int o=0;o<5;o++) store_out(out, g*5+o, lg[o]*inv);
        store_out(out, 328000 + g, acc[5] + valb[0]);
    }
}

// ---------------- node logits ----------------
__global__ __launch_bounds__(256) void k_nlog(const float* __restrict__ x,
                       const float* __restrict__ W,
                       const float* __restrict__ b, float* __restrict__ nl) {
    int n = blockIdx.x*256 + threadIdx.x;
    const float4* xr = (const float4*)(x + (size_t)n*EMB);
    float acc[5] = {b[0],b[1],b[2],b[3],b[4]};
    for (int k=0;k<32;k++){
        float4 v4 = xr[k];
        #pragma unroll
        for (int jj=0;jj<4;jj++){
            float v = (&v4.x)[jj];
            int k4 = k*4+jj;
            #pragma unroll
            for (int o=0;o<5;o++) acc[o] += v*W[k4*5+o];
        }
    }
    #pragma unroll
    for (int o=0;o<5;o++) nl[(size_t)n*5+o] = acc[o];
}

// ---------------- per-graph per-channel softmax over nodes ----------------
__global__ __launch_bounds__(256) void k_nodesm(const float* __restrict__ nl,
                         u32* __restrict__ out) {
    __shared__ float red[5][4];
    int g = blockIdx.x, t = threadIdx.x;
    float v[4][5];
    #pragma unroll
    for (int it=0; it<4; ++it){
        int n = g*NPG + it*256 + t;
        #pragma unroll
        for (int o=0;o<5;o++) v[it][o] = nl[(size_t)n*5+o];
    }
    float m[5];
    #pragma unroll
    for (int o=0;o<5;o++){
        float mm = fmaxf(fmaxf(v[0][o],v[1][o]),fmaxf(v[2][o],v[3][o]));
        #pragma unroll
        for (int d=1;d<64;d<<=1) mm = fmaxf(mm, __shfl_xor(mm,d));
        if ((t&63)==0) red[o][t>>6] = mm;
    }
    __syncthreads();
    #pragma unroll
    for (int o=0;o<5;o++)
        m[o] = fmaxf(fmaxf(red[o][0],red[o][1]),fmaxf(red[o][2],red[o][3]));
    __syncthreads();
    #pragma unroll
    for (int o=0;o<5;o++){
        float ss = 0.f;
        #pragma unroll
        for (int it=0;it<4;it++){ v[it][o] = expf(v[it][o]-m[o]); ss += v[it][o]; }
        #pragma unroll
        for (int d=1;d<64;d<<=1) ss += __shfl_xor(ss,d);
        if ((t&63)==0) red[o][t>>6] = ss;
    }
    __syncthreads();
    float s[5];
    #pragma unroll
    for (int o=0;o<5;o++)
        s[o] = 1.f/(red[o][0]+red[o][1]+red[o][2]+red[o][3]);
    #pragma unroll
    for (int it=0;it<4;it++){
        int n = g*NPG + it*256 + t;
        #pragma unroll
        for (int o=0;o<5;o++)
            store_out(out, 320 + n*5 + o, v[it][o]*s[o]);
    }
}

extern "C" void kernel_launch(void* const* d_in, const int* in_sizes, int n_in,
                              void* d_out, int out_size, void* d_ws, size_t ws_size,
                              hipStream_t stream) {
    const float* node_feats = (const float*)d_in[0];
    const float* edge_attr  = (const float*)d_in[1];
    const int*   edge_index = (const int*)d_in[2];
    const float* embed_W = (const float*)d_in[4];
    const float* embed_b = (const float*)d_in[5];
    const float* mess_W  = (const float*)d_in[6];
    const float* mess_b  = (const float*)d_in[7];
    const float* agg_W   = (const float*)d_in[8];
    const float* agg_b   = (const float*)d_in[9];
    const float* gate_W  = (const float*)d_in[10];
    const float* gate_b  = (const float*)d_in[11];
    const float* feat_W  = (const float*)d_in[12];
    const float* feat_b  = (const float*)d_in[13];
    const float* tr_W    = (const float*)d_in[14];
    const float* tr_b    = (const float*)d_in[15];
    const float* node_W  = (const float*)d_in[16];
    const float* node_b  = (const float*)d_in[17];
    const float* act_W   = (const float*)d_in[18];
    const float* act_b   = (const float*)d_in[19];
    const float* val_W   = (const float*)d_in[20];
    const float* val_b   = (const float*)d_in[21];

    // Workspace:
    //   x    f32 [0, 32MB)
    //   agg  f32 [32MB, 64MB)      (plain f32 now; fully written each step)
    //   w    = agg+0      (256KB)  alive gatepool->featpool
    //   xgn  = agg+256KB  (32KB)   alive gatepool->tr
    //   nl   = agg+0      (1.25MB) alive only after MP loop
    //   CSR at [64MiB, 69MiB): cnt, off, cursor, perm (1MB apart)
    // xg (32KB) stashed at d_out bytes [4096, 36864), overwritten by k_nodesm last.
    char* ws = (char*)d_ws;
    float* x    = (float*)(ws);
    float* agg  = (float*)(ws + 33554432);
    float* w    = (float*)(ws + 33554432);
    float* xgn  = (float*)(ws + 33554432 + 262144);
    float* nl   = (float*)(ws + 33554432);
    u32* cnt    = (u32*)(ws + 67108864);
    u32* off    = (u32*)(ws + 67108864 + 1048576);
    u32* cursor = (u32*)(ws + 67108864 + 2097152);
    u32* perm   = (u32*)(ws + 67108864 + 3145728);
    u32* out = (u32*)d_out;
    float* xg   = (float*)((char*)d_out + 4096);

    const int* srcv = edge_index;
    const int* dstv = edge_index + NE;

    // CSR build (once per launch; perm order nondeterministic, max is
    // order-independent -> output deterministic)
    hipMemsetAsync(cnt, 0, NTOT*sizeof(u32), stream);
    k_count  <<<NE/256, 256, 0, stream>>>(dstv, cnt);
    k_scan   <<<1, 1024, 0, stream>>>(cnt, off, cursor);
    k_scatter<<<NE/256, 256, 0, stream>>>(dstv, cursor, perm);

    hipMemsetAsync(xg, 0, NG*EMB*sizeof(float), stream);
    k_embed<<<NTOT*EMB/256, 256, 0, stream>>>(node_feats, embed_W, embed_b, x);

    for (int i=0;i<STEPS;i++){
        k_msgmax<<<NTOT/16, 256, 0, stream>>>(x, edge_attr, srcv, dstv, off, perm,
            mess_W + (size_t)i*132*EMB, mess_b + i*EMB, agg);
        k_aggupd<<<NTOT/8, 256, 0, stream>>>(x, xg, agg,
            agg_W + (size_t)i*384*EMB, agg_b + i*EMB);
        k_gatepool<<<NG, 256, 0, stream>>>(x, gate_W + i*EMB, gate_b + i, w, xgn);
        k_featpool<<<NG*16, 256, 0, stream>>>(x, w,
            feat_W + (size_t)i*EMB*EMB, feat_b + i*EMB, xgn);
        k_tr<<<NG, 128, 0, stream>>>(xg, xgn, tr_W + (size_t)i*256*EMB, tr_b + i*EMB);
    }

    k_ghead<<<NG, 64, 0, stream>>>(xg, act_W, act_b, val_W, val_b, out);
    k_nlog<<<NTOT/256, 256, 0, stream>>>(x, node_W, node_b, nl);
    k_nodesm<<<NG, 256, 0, stream>>>(nl, out);
}

// Round 12
// 2778.231 us; speedup vs baseline: 4.0887x; 2.3876x over previous
//
#include <hip/hip_runtime.h>
#include <hip/hip_bf16.h>

#define NTOT  65536
#define NE    524288
#define NG    64
#define NPG   1024
#define EMB   128
#define STEPS 4

typedef unsigned short u16;
typedef unsigned int   u32;

__device__ __forceinline__ float lrelu(float v){ return v > 0.f ? v : 0.01f*v; }
__device__ __forceinline__ u16 f2bf(float f){
    u32 u = __float_as_uint(f);
    u32 r = (u + 0x7FFFu + ((u>>16)&1u)) >> 16;   // round-to-nearest-even
    return (u16)r;
}
__device__ __forceinline__ void store_out(u32* out, int j, float v){
    u32 b = (u32)f2bf(v);
    out[j] = (b << 16) | b;      // bf16 bits in both u16 halves of slot j
}

// ================= CSR build (once per launch) =================
__global__ __launch_bounds__(256) void k_count(const int* __restrict__ dstv,
                                               u32* __restrict__ cnt){
    int e = blockIdx.x*256 + threadIdx.x;
    atomicAdd(&cnt[dstv[e]], 1u);
}

__global__ __launch_bounds__(1024) void k_scan(const u32* __restrict__ cnt,
                                               u32* __restrict__ off,
                                               u32* __restrict__ cursor){
    __shared__ u32 part[1024];
    int t = threadIdx.x;
    u32 s = 0;
    for (int i=0;i<64;i++) s += cnt[t*64+i];
    part[t] = s; __syncthreads();
    for (int d=1; d<1024; d<<=1){
        u32 v = (t>=d) ? part[t-d] : 0u;
        __syncthreads();
        part[t] += v;
        __syncthreads();
    }
    u32 base = (t==0) ? 0u : part[t-1];
    for (int i=0;i<64;i++){
        off[t*64+i] = base; cursor[t*64+i] = base;
        base += cnt[t*64+i];
    }
    if (t==1023) off[65536] = base;
}

__global__ __launch_bounds__(256) void k_scatter(const int* __restrict__ dstv,
                                                 u32* __restrict__ cursor,
                                                 u32* __restrict__ perm){
    int e = blockIdx.x*256 + threadIdx.x;
    u32 pos = atomicAdd(&cursor[dstv[e]], 1u);
    perm[pos] = e;
}

// ---------------- embed: x = lrelu(nf @ W + b) ----------------
__global__ __launch_bounds__(256) void k_embed(const float* __restrict__ nf,
                        const float* __restrict__ W,
                        const float* __restrict__ b, float* __restrict__ x) {
    int idx = blockIdx.x*256 + threadIdx.x;
    int n = idx >> 7, c = idx & 127;
    const float* f = nf + n*5;
    float acc = b[c];
    #pragma unroll
    for (int k=0;k<5;k++) acc += f[k]*W[k*EMB+c];
    x[idx] = lrelu(acc);
}

// ---------------- xw = x @ W_x + b (per-node, reused by all out-edges) ----------------
// block: 256 = 16 nodes x 16 colgroups(8); W_x = mess_W rows [0,128)
__global__ __launch_bounds__(256) void k_xw(const float* __restrict__ x,
                        const float* __restrict__ W,
                        const float* __restrict__ b, float* __restrict__ xw) {
    __shared__ float xs[16][128];
    int n0 = blockIdx.x*16;
    int t = threadIdx.x;
    for (int i=t;i<16*128;i+=256){
        int l=i>>7, k=i&127;
        xs[l][k] = x[(size_t)(n0+l)*EMB + k];
    }
    __syncthreads();
    int le=t>>4, c=(t&15)*8;
    float acc[8];
    #pragma unroll
    for (int q=0;q<8;q++) acc[q] = b[c+q];
    for (int k=0;k<128;k++){
        float v = xs[le][k];
        const float4 w0 = *(const float4*)(W + (size_t)k*EMB + c);
        const float4 w1 = *(const float4*)(W + (size_t)k*EMB + c + 4);
        acc[0]+=v*w0.x; acc[1]+=v*w0.y; acc[2]+=v*w0.z; acc[3]+=v*w0.w;
        acc[4]+=v*w1.x; acc[5]+=v*w1.y; acc[6]+=v*w1.z; acc[7]+=v*w1.w;
    }
    float* o = xw + (size_t)(n0+le)*EMB + c;
    #pragma unroll
    for (int q=0;q<8;q++) o[q] = acc[q];
}

// ---------------- gather-max: agg[n] = max_e lrelu(xw[src]+ea@W_ea), no barriers ----------------
// block: 256 = 16 dst nodes x 16 colgroups(8). W_ea = mess_W rows [128,132).
__global__ __launch_bounds__(256) void k_msgmax2(const float* __restrict__ xw,
                          const float* __restrict__ ea,
                          const int* __restrict__ srcv,
                          const u32* __restrict__ off, const u32* __restrict__ perm,
                          const float* __restrict__ Wea,
                          float* __restrict__ agg) {
    int t = threadIdx.x;
    int le = t>>4, c = (t&15)*8;
    int n = blockIdx.x*16 + le;
    // W_ea columns for this thread -> 32 registers
    float we[4][8];
    #pragma unroll
    for (int r=0;r<4;r++)
        #pragma unroll
        for (int q=0;q<8;q++) we[r][q] = Wea[r*EMB + c + q];
    u32 j0 = off[n], j1 = off[n+1];
    float racc[8];
    #pragma unroll
    for (int q=0;q<8;q++) racc[q] = -INFINITY;
    for (u32 j=j0; j<j1; ++j){
        u32 e = perm[j];
        int s = srcv[e];
        const float4 ev = *(const float4*)(ea + (size_t)e*4);
        const float4 x0 = *(const float4*)(xw + (size_t)s*EMB + c);
        const float4 x1 = *(const float4*)(xw + (size_t)s*EMB + c + 4);
        float m[8];
        m[0]=x0.x; m[1]=x0.y; m[2]=x0.z; m[3]=x0.w;
        m[4]=x1.x; m[5]=x1.y; m[6]=x1.z; m[7]=x1.w;
        #pragma unroll
        for (int q=0;q<8;q++){
            m[q] += ev.x*we[0][q] + ev.y*we[1][q] + ev.z*we[2][q] + ev.w*we[3][q];
            racc[q] = fmaxf(racc[q], lrelu(m[q]));
        }
    }
    float* o = agg + (size_t)n*EMB + c;
    #pragma unroll
    for (int q=0;q<8;q++) o[q] = (racc[q] == -INFINITY) ? 0.f : racc[q];
}

// ---------------- x = lrelu([x, xg[b], agg] @ W + b) + x ----------------
__global__ __launch_bounds__(256) void k_aggupd(float* __restrict__ x,
                         const float* __restrict__ xg,
                         const float* __restrict__ agg,
                         const float* __restrict__ W, const float* __restrict__ b) {
    __shared__ float in[8][384];
    int n0 = blockIdx.x*8;
    int t = threadIdx.x;
    for (int i=t;i<8*384;i+=256){
        int ln = i/384, k = i - ln*384;
        int n = n0+ln;
        float v;
        if (k<128)       v = x[(size_t)n*EMB+k];
        else if (k<256)  v = xg[(n>>10)*EMB + (k-128)];
        else             v = agg[(size_t)n*EMB + (k-256)];
        in[ln][k]=v;
    }
    __syncthreads();
    int ln=t>>5, c=(t&31)*4, n=n0+ln;
    float4 acc = make_float4(b[c],b[c+1],b[c+2],b[c+3]);
    for (int k=0;k<384;k++){
        float v = in[ln][k];
        const float4 w4 = *(const float4*)(W + (size_t)k*EMB + c);
        acc.x += v*w4.x; acc.y += v*w4.y; acc.z += v*w4.z; acc.w += v*w4.w;
    }
    float* xp = x + (size_t)n*EMB + c;
    xp[0] = lrelu(acc.x) + in[ln][c];
    xp[1] = lrelu(acc.y) + in[ln][c+1];
    xp[2] = lrelu(acc.z) + in[ln][c+2];
    xp[3] = lrelu(acc.w) + in[ln][c+3];
}

// ---------------- gate + per-graph softmax weights ----------------
__global__ __launch_bounds__(256) void k_gatepool(const float* __restrict__ x,
                           const float* __restrict__ gw,
                           const float* __restrict__ gb, float* __restrict__ w,
                           float* __restrict__ xgn) {
    __shared__ float red[4];
    __shared__ float bmax, bsum;
    int g = blockIdx.x, t = threadIdx.x;
    if (t < EMB) xgn[g*EMB + t] = 0.f;
    float gv[4];
    #pragma unroll
    for (int j=0;j<4;j++){
        int n = g*NPG + j*256 + t;
        const float4* xr = (const float4*)(x + (size_t)n*EMB);
        float acc = 0.f;
        for (int k=0;k<EMB/4;k++){
            float4 v = xr[k];
            float4 gw4 = ((const float4*)gw)[k];
            acc += v.x*gw4.x + v.y*gw4.y + v.z*gw4.z + v.w*gw4.w;
        }
        gv[j] = acc + gb[0];
    }
    float m = fmaxf(fmaxf(gv[0],gv[1]),fmaxf(gv[2],gv[3]));
    #pragma unroll
    for (int o=1;o<64;o<<=1) m = fmaxf(m, __shfl_xor(m, o));
    int wv = t>>6;
    if ((t&63)==0) red[wv] = m;
    __syncthreads();
    if (t==0) bmax = fmaxf(fmaxf(red[0],red[1]), fmaxf(red[2],red[3]));
    __syncthreads();
    m = bmax;
    float e[4]; float s = 0.f;
    #pragma unroll
    for (int j=0;j<4;j++){ e[j] = expf(gv[j]-m); s += e[j]; }
    #pragma unroll
    for (int o=1;o<64;o<<=1) s += __shfl_xor(s, o);
    __syncthreads();
    if ((t&63)==0) red[wv] = s;
    __syncthreads();
    if (t==0) bsum = red[0]+red[1]+red[2]+red[3];
    __syncthreads();
    float inv = 1.f/bsum;
    #pragma unroll
    for (int j=0;j<4;j++){
        int n = g*NPG + j*256 + t;
        w[n] = e[j]*inv;
    }
}

// ---------------- feat = lrelu(x @ fW + fb); xg_new += w[n]*feat ----------------
__global__ __launch_bounds__(256) void k_featpool(const float* __restrict__ x,
                           const float* __restrict__ w,
                           const float* __restrict__ W, const float* __restrict__ b,
                           float* __restrict__ xgn) {
    __shared__ float Wh[EMB][64];
    __shared__ float xr[4][EMB];
    __shared__ float red[4][64];
    int bid = blockIdx.x;
    int ch = bid & 1, chunk = (bid>>1)&7, g = bid>>4;
    int c0 = ch*64;
    int t = threadIdx.x;
    for (int i=t;i<EMB*64;i+=256){
        int k=i>>6, c=i&63;
        Wh[k][c] = W[(size_t)k*EMB + c0 + c];
    }
    int tn = t>>6, tc = t&63;
    float bias = b[c0+tc];
    float sum = 0.f;
    int nbase = g*NPG + chunk*128;
    for (int it=0; it<32; ++it){
        __syncthreads();
        for (int i=t;i<4*EMB;i+=256){
            int ln=i>>7, k=i&127;
            xr[ln][k] = x[(size_t)(nbase + it*4 + ln)*EMB + k];
        }
        __syncthreads();
        float acc = bias;
        #pragma unroll 16
        for (int k=0;k<EMB;k++) acc += xr[tn][k]*Wh[k][tc];
        int n = nbase + it*4 + tn;
        sum += w[n]*lrelu(acc);
    }
    red[tn][tc] = sum;
    __syncthreads();
    if (t<64){
        float s = red[0][t]+red[1][t]+red[2][t]+red[3][t];
        atomicAdd(&xgn[g*EMB + c0 + t], s);
    }
}

// ---------------- xg = lrelu([xg_new, xg] @ W + b) + xg ----------------
__global__ __launch_bounds__(128) void k_tr(float* __restrict__ xg,
                     const float* __restrict__ xgn,
                     const float* __restrict__ W, const float* __restrict__ b) {
    __shared__ float in[256];
    int g = blockIdx.x, t = threadIdx.x;
    in[t]     = xgn[g*EMB + t];
    in[128+t] = xg[g*EMB + t];
    __syncthreads();
    float acc = b[t];
    for (int k=0;k<256;k++) acc += in[k]*W[(size_t)k*EMB + t];
    xg[g*EMB+t] = lrelu(acc) + in[128+t];
}

// ---------------- graph heads: a_probs + value ----------------
__global__ __launch_bounds__(64) void k_ghead(const float* __restrict__ xg,
                        const float* __restrict__ actW, const float* __restrict__ actb,
                        const float* __restrict__ valW, const float* __restrict__ valb,
                        u32* __restrict__ out) {
    int g = blockIdx.x, l = threadIdx.x;
    float xa = xg[g*EMB + l], xb = xg[g*EMB + 64 + l];
    float acc[6];
    #pragma unroll
    for (int o=0;o<5;o++) acc[o] = xa*actW[l*5+o] + xb*actW[(l+64)*5+o];
    acc[5] = xa*valW[l] + xb*valW[64+l];
    #pragma unroll
    for (int o=0;o<6;o++){
        float sv = acc[o];
        #pragma unroll
        for (int d=1;d<64;d<<=1) sv += __shfl_xor(sv, d);
        acc[o] = sv;
    }
    if (l==0){
        float lg[5], m = -1e30f;
        #pragma unroll
        for (int o=0;o<5;o++){ lg[o]=acc[o]+actb[o]; m = fmaxf(m, lg[o]); }
        float ssum=0.f;
        #pragma unroll
        for (int o=0;o<5;o++){ lg[o]=expf(lg[o]-m); ssum+=lg[o]; }
        float inv = 1.f/ssum;
        #pragma unroll
        for (int o=0;o<5;o++) store_out(out, g*5+o, lg[o]*inv);
        store_out(out, 328000 + g, acc[5] + valb[0]);
    }
}

// ---------------- node logits ----------------
__global__ __launch_bounds__(256) void k_nlog(const float* __restrict__ x,
                       const float* __restrict__ W,
                       const float* __restrict__ b, float* __restrict__ nl) {
    int n = blockIdx.x*256 + threadIdx.x;
    const float4* xr = (const float4*)(x + (size_t)n*EMB);
    float acc[5] = {b[0],b[1],b[2],b[3],b[4]};
    for (int k=0;k<32;k++){
        float4 v4 = xr[k];
        #pragma unroll
        for (int jj=0;jj<4;jj++){
            float v = (&v4.x)[jj];
            int k4 = k*4+jj;
            #pragma unroll
            for (int o=0;o<5;o++) acc[o] += v*W[k4*5+o];
        }
    }
    #pragma unroll
    for (int o=0;o<5;o++) nl[(size_t)n*5+o] = acc[o];
}

// ---------------- per-graph per-channel softmax over nodes ----------------
__global__ __launch_bounds__(256) void k_nodesm(const float* __restrict__ nl,
                         u32* __restrict__ out) {
    __shared__ float red[5][4];
    int g = blockIdx.x, t = threadIdx.x;
    float v[4][5];
    #pragma unroll
    for (int it=0; it<4; ++it){
        int n = g*NPG + it*256 + t;
        #pragma unroll
        for (int o=0;o<5;o++) v[it][o] = nl[(size_t)n*5+o];
    }
    float m[5];
    #pragma unroll
    for (int o=0;o<5;o++){
        float mm = fmaxf(fmaxf(v[0][o],v[1][o]),fmaxf(v[2][o],v[3][o]));
        #pragma unroll
        for (int d=1;d<64;d<<=1) mm = fmaxf(mm, __shfl_xor(mm,d));
        if ((t&63)==0) red[o][t>>6] = mm;
    }
    __syncthreads();
    #pragma unroll
    for (int o=0;o<5;o++)
        m[o] = fmaxf(fmaxf(red[o][0],red[o][1]),fmaxf(red[o][2],red[o][3]));
    __syncthreads();
    #pragma unroll
    for (int o=0;o<5;o++){
        float ss = 0.f;
        #pragma unroll
        for (int it=0;it<4;it++){ v[it][o] = expf(v[it][o]-m[o]); ss += v[it][o]; }
        #pragma unroll
        for (int d=1;d<64;d<<=1) ss += __shfl_xor(ss,d);
        if ((t&63)==0) red[o][t>>6] = ss;
    }
    __syncthreads();
    float s[5];
    #pragma unroll
    for (int o=0;o<5;o++)
        s[o] = 1.f/(red[o][0]+red[o][1]+red[o][2]+red[o][3]);
    #pragma unroll
    for (int it=0;it<4;it++){
        int n = g*NPG + it*256 + t;
        #pragma unroll
        for (int o=0;o<5;o++)
            store_out(out, 320 + n*5 + o, v[it][o]*s[o]);
    }
}

extern "C" void kernel_launch(void* const* d_in, const int* in_sizes, int n_in,
                              void* d_out, int out_size, void* d_ws, size_t ws_size,
                              hipStream_t stream) {
    const float* node_feats = (const float*)d_in[0];
    const float* edge_attr  = (const float*)d_in[1];
    const int*   edge_index = (const int*)d_in[2];
    const float* embed_W = (const float*)d_in[4];
    const float* embed_b = (const float*)d_in[5];
    const float* mess_W  = (const float*)d_in[6];
    const float* mess_b  = (const float*)d_in[7];
    const float* agg_W   = (const float*)d_in[8];
    const float* agg_b   = (const float*)d_in[9];
    const float* gate_W  = (const float*)d_in[10];
    const float* gate_b  = (const float*)d_in[11];
    const float* feat_W  = (const float*)d_in[12];
    const float* feat_b  = (const float*)d_in[13];
    const float* tr_W    = (const float*)d_in[14];
    const float* tr_b    = (const float*)d_in[15];
    const float* node_W  = (const float*)d_in[16];
    const float* node_b  = (const float*)d_in[17];
    const float* act_W   = (const float*)d_in[18];
    const float* act_b   = (const float*)d_in[19];
    const float* val_W   = (const float*)d_in[20];
    const float* val_b   = (const float*)d_in[21];

    // Workspace:
    //   x    f32 [0, 32M)
    //   agg  f32 [32M, 64M)  (w/xgn/nl aliased inside, same liveness as before)
    //   CSR  [64MiB..69MiB): cnt(256K) off(257K->1M slot) cursor(1M) perm(2M)
    //   xw   f32 [72MiB, 104MiB)
    // xg (32KB) stashed at d_out bytes [4096, 36864), overwritten by k_nodesm last.
    char* ws = (char*)d_ws;
    float* x    = (float*)(ws);
    float* agg  = (float*)(ws + 33554432);
    float* w    = (float*)(ws + 33554432);
    float* xgn  = (float*)(ws + 33554432 + 262144);
    float* nl   = (float*)(ws + 33554432);
    u32* cnt    = (u32*)(ws + 67108864);
    u32* off    = (u32*)(ws + 67108864 + 1048576);
    u32* cursor = (u32*)(ws + 67108864 + 2097152);
    u32* perm   = (u32*)(ws + 67108864 + 3145728);
    float* xw   = (float*)(ws + 75497472);
    u32* out = (u32*)d_out;
    float* xg   = (float*)((char*)d_out + 4096);

    const int* srcv = edge_index;
    const int* dstv = edge_index + NE;

    // CSR build (once per launch; perm order nondeterministic, max is
    // order-independent -> output deterministic)
    hipMemsetAsync(cnt, 0, NTOT*sizeof(u32), stream);
    k_count  <<<NE/256, 256, 0, stream>>>(dstv, cnt);
    k_scan   <<<1, 1024, 0, stream>>>(cnt, off, cursor);
    k_scatter<<<NE/256, 256, 0, stream>>>(dstv, cursor, perm);

    hipMemsetAsync(xg, 0, NG*EMB*sizeof(float), stream);
    k_embed<<<NTOT*EMB/256, 256, 0, stream>>>(node_feats, embed_W, embed_b, x);

    for (int i=0;i<STEPS;i++){
        const float* Wm = mess_W + (size_t)i*132*EMB;
        k_xw<<<NTOT/16, 256, 0, stream>>>(x, Wm, mess_b + i*EMB, xw);
        k_msgmax2<<<NTOT/16, 256, 0, stream>>>(xw, edge_attr, srcv, off, perm,
            Wm + (size_t)128*EMB, agg);
        k_aggupd<<<NTOT/8, 256, 0, stream>>>(x, xg, agg,
            agg_W + (size_t)i*384*EMB, agg_b + i*EMB);
        k_gatepool<<<NG, 256, 0, stream>>>(x, gate_W + i*EMB, gate_b + i, w, xgn);
        k_featpool<<<NG*16, 256, 0, stream>>>(x, w,
            feat_W + (size_t)i*EMB*EMB, feat_b + i*EMB, xgn);
        k_tr<<<NG, 128, 0, stream>>>(xg, xgn, tr_W + (size_t)i*256*EMB, tr_b + i*EMB);
    }

    k_ghead<<<NG, 64, 0, stream>>>(xg, act_W, act_b, val_W, val_b, out);
    k_nlog<<<NTOT/256, 256, 0, stream>>>(x, node_W, node_b, nl);
    k_nodesm<<<NG, 256, 0, stream>>>(nl, out);
}

// Round 13
// 1878.038 us; speedup vs baseline: 6.0485x; 1.4793x over previous
//
#include <hip/hip_runtime.h>
#include <hip/hip_bf16.h>

#define NTOT  65536
#define NE    524288
#define NG    64
#define NPG   1024
#define EMB   128
#define STEPS 4

typedef unsigned short u16;
typedef unsigned int   u32;

__device__ __forceinline__ float lrelu(float v){ return v > 0.f ? v : 0.01f*v; }
__device__ __forceinline__ u16 f2bf(float f){
    u32 u = __float_as_uint(f);
    u32 r = (u + 0x7FFFu + ((u>>16)&1u)) >> 16;   // round-to-nearest-even
    return (u16)r;
}
__device__ __forceinline__ void store_out(u32* out, int j, float v){
    u32 b = (u32)f2bf(v);
    out[j] = (b << 16) | b;      // bf16 bits in both u16 halves of slot j
}

// ================= CSR build (once per launch) =================
__global__ __launch_bounds__(256) void k_count(const int* __restrict__ dstv,
                                               u32* __restrict__ cnt){
    int e = blockIdx.x*256 + threadIdx.x;
    atomicAdd(&cnt[dstv[e]], 1u);
}

__global__ __launch_bounds__(1024) void k_scan(const u32* __restrict__ cnt,
                                               u32* __restrict__ off,
                                               u32* __restrict__ cursor){
    __shared__ u32 part[1024];
    int t = threadIdx.x;
    u32 s = 0;
    for (int i=0;i<64;i++) s += cnt[t*64+i];
    part[t] = s; __syncthreads();
    for (int d=1; d<1024; d<<=1){
        u32 v = (t>=d) ? part[t-d] : 0u;
        __syncthreads();
        part[t] += v;
        __syncthreads();
    }
    u32 base = (t==0) ? 0u : part[t-1];
    for (int i=0;i<64;i++){
        off[t*64+i] = base; cursor[t*64+i] = base;
        base += cnt[t*64+i];
    }
    if (t==1023) off[65536] = base;
}

__global__ __launch_bounds__(256) void k_scatter(const int* __restrict__ dstv,
                                                 u32* __restrict__ cursor,
                                                 u32* __restrict__ perm){
    int e = blockIdx.x*256 + threadIdx.x;
    u32 pos = atomicAdd(&cursor[dstv[e]], 1u);
    perm[pos] = e;
}

// ---------------- embed: x = lrelu(nf @ W + b) ----------------
__global__ __launch_bounds__(256) void k_embed(const float* __restrict__ nf,
                        const float* __restrict__ W,
                        const float* __restrict__ b, float* __restrict__ x) {
    int idx = blockIdx.x*256 + threadIdx.x;
    int n = idx >> 7, c = idx & 127;
    const float* f = nf + n*5;
    float acc = b[c];
    #pragma unroll
    for (int k=0;k<5;k++) acc += f[k]*W[k*EMB+c];
    x[idx] = lrelu(acc);
}

// ---------------- xw = x @ W_x + b (per-node, reused by all out-edges) ----------------
__global__ __launch_bounds__(256) void k_xw(const float* __restrict__ x,
                        const float* __restrict__ W,
                        const float* __restrict__ b, float* __restrict__ xw) {
    __shared__ float xs[16][128];
    int n0 = blockIdx.x*16;
    int t = threadIdx.x;
    for (int i=t;i<16*128;i+=256){
        int l=i>>7, k=i&127;
        xs[l][k] = x[(size_t)(n0+l)*EMB + k];
    }
    __syncthreads();
    int le=t>>4, c=(t&15)*8;
    float acc[8];
    #pragma unroll
    for (int q=0;q<8;q++) acc[q] = b[c+q];
    for (int k=0;k<128;k++){
        float v = xs[le][k];
        const float4 w0 = *(const float4*)(W + (size_t)k*EMB + c);
        const float4 w1 = *(const float4*)(W + (size_t)k*EMB + c + 4);
        acc[0]+=v*w0.x; acc[1]+=v*w0.y; acc[2]+=v*w0.z; acc[3]+=v*w0.w;
        acc[4]+=v*w1.x; acc[5]+=v*w1.y; acc[6]+=v*w1.z; acc[7]+=v*w1.w;
    }
    float* o = xw + (size_t)(n0+le)*EMB + c;
    #pragma unroll
    for (int q=0;q<8;q++) o[q] = acc[q];
}

// ---------------- gather-max: agg[n] = max_e lrelu(xw[src]+ea@W_ea) ----------------
__global__ __launch_bounds__(256) void k_msgmax2(const float* __restrict__ xw,
                          const float* __restrict__ ea,
                          const int* __restrict__ srcv,
                          const u32* __restrict__ off, const u32* __restrict__ perm,
                          const float* __restrict__ Wea,
                          float* __restrict__ agg) {
    int t = threadIdx.x;
    int le = t>>4, c = (t&15)*8;
    int n = blockIdx.x*16 + le;
    float we[4][8];
    #pragma unroll
    for (int r=0;r<4;r++)
        #pragma unroll
        for (int q=0;q<8;q++) we[r][q] = Wea[r*EMB + c + q];
    u32 j0 = off[n], j1 = off[n+1];
    float racc[8];
    #pragma unroll
    for (int q=0;q<8;q++) racc[q] = -INFINITY;
    for (u32 j=j0; j<j1; ++j){
        u32 e = perm[j];
        int s = srcv[e];
        const float4 ev = *(const float4*)(ea + (size_t)e*4);
        const float4 x0 = *(const float4*)(xw + (size_t)s*EMB + c);
        const float4 x1 = *(const float4*)(xw + (size_t)s*EMB + c + 4);
        float m[8];
        m[0]=x0.x; m[1]=x0.y; m[2]=x0.z; m[3]=x0.w;
        m[4]=x1.x; m[5]=x1.y; m[6]=x1.z; m[7]=x1.w;
        #pragma unroll
        for (int q=0;q<8;q++){
            m[q] += ev.x*we[0][q] + ev.y*we[1][q] + ev.z*we[2][q] + ev.w*we[3][q];
            racc[q] = fmaxf(racc[q], lrelu(m[q]));
        }
    }
    float* o = agg + (size_t)n*EMB + c;
    #pragma unroll
    for (int q=0;q<8;q++) o[q] = (racc[q] == -INFINITY) ? 0.f : racc[q];
}

// ---------------- x = lrelu([x, xg[b], agg] @ W + b) + x  (tiled GEMM) ----------------
// tile: 32 nodes x 128 cols; thread = 4 nodes x 4 cols (64 FMA / 4 LDS b128)
__global__ __launch_bounds__(256) void k_aggupd(float* __restrict__ x,
                         const float* __restrict__ xg,
                         const float* __restrict__ agg,
                         const float* __restrict__ W, const float* __restrict__ b) {
    __shared__ float in[32][384];     // 48 KB
    __shared__ float Wt[32][128];     // 16 KB
    int n0 = blockIdx.x*32;
    int t = threadIdx.x;
    for (int i=t; i<32*96; i+=256){
        int ln = i/96, kq = i - ln*96;
        int n = n0+ln;
        float4 v;
        if (kq < 32)       v = *(const float4*)(x   + (size_t)n*EMB + kq*4);
        else if (kq < 64)  v = *(const float4*)(xg  + (size_t)(n>>10)*EMB + (kq-32)*4);
        else               v = *(const float4*)(agg + (size_t)n*EMB + (kq-64)*4);
        *(float4*)(&in[ln][kq*4]) = v;
    }
    int ng = t>>5, cg = t&31;
    int c = cg*4;
    float4 bv = *(const float4*)(b + c);
    float4 acc0 = bv, acc1 = bv, acc2 = bv, acc3 = bv;
    for (int kt=0; kt<12; ++kt){
        __syncthreads();
        for (int i=t; i<32*32; i+=256){
            int r = i>>5, q4 = i&31;
            *(float4*)(&Wt[r][q4*4]) =
                *(const float4*)(W + (size_t)(kt*32+r)*EMB + q4*4);
        }
        __syncthreads();
        #pragma unroll
        for (int k4=0; k4<8; ++k4){
            int kb = k4*4;
            float4 a0 = *(const float4*)(&in[ng*4+0][kt*32 + kb]);
            float4 a1 = *(const float4*)(&in[ng*4+1][kt*32 + kb]);
            float4 a2 = *(const float4*)(&in[ng*4+2][kt*32 + kb]);
            float4 a3 = *(const float4*)(&in[ng*4+3][kt*32 + kb]);
            #pragma unroll
            for (int kk=0;kk<4;kk++){
                float4 w4 = *(const float4*)(&Wt[kb+kk][c]);
                float aj;
                aj = (&a0.x)[kk];
                acc0.x+=aj*w4.x; acc0.y+=aj*w4.y; acc0.z+=aj*w4.z; acc0.w+=aj*w4.w;
                aj = (&a1.x)[kk];
                acc1.x+=aj*w4.x; acc1.y+=aj*w4.y; acc1.z+=aj*w4.z; acc1.w+=aj*w4.w;
                aj = (&a2.x)[kk];
                acc2.x+=aj*w4.x; acc2.y+=aj*w4.y; acc2.z+=aj*w4.z; acc2.w+=aj*w4.w;
                aj = (&a3.x)[kk];
                acc3.x+=aj*w4.x; acc3.y+=aj*w4.y; acc3.z+=aj*w4.z; acc3.w+=aj*w4.w;
            }
        }
    }
    float4 av[4] = {acc0, acc1, acc2, acc3};
    #pragma unroll
    for (int j=0;j<4;j++){
        int ln = ng*4 + j;
        float* xp = x + (size_t)(n0+ln)*EMB + c;
        xp[0] = lrelu(av[j].x) + in[ln][c];
        xp[1] = lrelu(av[j].y) + in[ln][c+1];
        xp[2] = lrelu(av[j].z) + in[ln][c+2];
        xp[3] = lrelu(av[j].w) + in[ln][c+3];
    }
}

// ---------------- gate + per-graph softmax weights ----------------
__global__ __launch_bounds__(256) void k_gatepool(const float* __restrict__ x,
                           const float* __restrict__ gw,
                           const float* __restrict__ gb, float* __restrict__ w,
                           float* __restrict__ xgn) {
    __shared__ float red[4];
    __shared__ float bmax, bsum;
    int g = blockIdx.x, t = threadIdx.x;
    if (t < EMB) xgn[g*EMB + t] = 0.f;
    float gv[4];
    #pragma unroll
    for (int j=0;j<4;j++){
        int n = g*NPG + j*256 + t;
        const float4* xr = (const float4*)(x + (size_t)n*EMB);
        float acc = 0.f;
        for (int k=0;k<EMB/4;k++){
            float4 v = xr[k];
            float4 gw4 = ((const float4*)gw)[k];
            acc += v.x*gw4.x + v.y*gw4.y + v.z*gw4.z + v.w*gw4.w;
        }
        gv[j] = acc + gb[0];
    }
    float m = fmaxf(fmaxf(gv[0],gv[1]),fmaxf(gv[2],gv[3]));
    #pragma unroll
    for (int o=1;o<64;o<<=1) m = fmaxf(m, __shfl_xor(m, o));
    int wv = t>>6;
    if ((t&63)==0) red[wv] = m;
    __syncthreads();
    if (t==0) bmax = fmaxf(fmaxf(red[0],red[1]), fmaxf(red[2],red[3]));
    __syncthreads();
    m = bmax;
    float e[4]; float s = 0.f;
    #pragma unroll
    for (int j=0;j<4;j++){ e[j] = expf(gv[j]-m); s += e[j]; }
    #pragma unroll
    for (int o=1;o<64;o<<=1) s += __shfl_xor(s, o);
    __syncthreads();
    if ((t&63)==0) red[wv] = s;
    __syncthreads();
    if (t==0) bsum = red[0]+red[1]+red[2]+red[3];
    __syncthreads();
    float inv = 1.f/bsum;
    #pragma unroll
    for (int j=0;j<4;j++){
        int n = g*NPG + j*256 + t;
        w[n] = e[j]*inv;
    }
}

// ---------------- feat = lrelu(x @ fW + fb); xg_new += w[n]*feat ----------------
__global__ __launch_bounds__(256) void k_featpool(const float* __restrict__ x,
                           const float* __restrict__ w,
                           const float* __restrict__ W, const float* __restrict__ b,
                           float* __restrict__ xgn) {
    __shared__ float Wh[EMB][64];
    __shared__ float xr[4][EMB];
    __shared__ float red[4][64];
    int bid = blockIdx.x;
    int ch = bid & 1, chunk = (bid>>1)&7, g = bid>>4;
    int c0 = ch*64;
    int t = threadIdx.x;
    for (int i=t;i<EMB*64;i+=256){
        int k=i>>6, c=i&63;
        Wh[k][c] = W[(size_t)k*EMB + c0 + c];
    }
    int tn = t>>6, tc = t&63;
    float bias = b[c0+tc];
    float sum = 0.f;
    int nbase = g*NPG + chunk*128;
    for (int it=0; it<32; ++it){
        __syncthreads();
        for (int i=t;i<4*EMB;i+=256){
            int ln=i>>7, k=i&127;
            xr[ln][k] = x[(size_t)(nbase + it*4 + ln)*EMB + k];
        }
        __syncthreads();
        float acc = bias;
        #pragma unroll 16
        for (int k=0;k<EMB;k++) acc += xr[tn][k]*Wh[k][tc];
        int n = nbase + it*4 + tn;
        sum += w[n]*lrelu(acc);
    }
    red[tn][tc] = sum;
    __syncthreads();
    if (t<64){
        float s = red[0][t]+red[1][t]+red[2][t]+red[3][t];
        atomicAdd(&xgn[g*EMB + c0 + t], s);
    }
}

// ---------------- xg = lrelu([xg_new, xg] @ W + b) + xg ----------------
__global__ __launch_bounds__(128) void k_tr(float* __restrict__ xg,
                     const float* __restrict__ xgn,
                     const float* __restrict__ W, const float* __restrict__ b) {
    __shared__ float in[256];
    int g = blockIdx.x, t = threadIdx.x;
    in[t]     = xgn[g*EMB + t];
    in[128+t] = xg[g*EMB + t];
    __syncthreads();
    float acc = b[t];
    for (int k=0;k<256;k++) acc += in[k]*W[(size_t)k*EMB + t];
    xg[g*EMB+t] = lrelu(acc) + in[128+t];
}

// ---------------- graph heads: a_probs + value ----------------
__global__ __launch_bounds__(64) void k_ghead(const float* __restrict__ xg,
                        const float* __restrict__ actW, const float* __restrict__ actb,
                        const float* __restrict__ valW, const float* __restrict__ valb,
                        u32* __restrict__ out) {
    int g = blockIdx.x, l = threadIdx.x;
    float xa = xg[g*EMB + l], xb = xg[g*EMB + 64 + l];
    float acc[6];
    #pragma unroll
    for (int o=0;o<5;o++) acc[o] = xa*actW[l*5+o] + xb*actW[(l+64)*5+o];
    acc[5] = xa*valW[l] + xb*valW[64+l];
    #pragma unroll
    for (int o=0;o<6;o++){
        float sv = acc[o];
        #pragma unroll
        for (int d=1;d<64;d<<=1) sv += __shfl_xor(sv, d);
        acc[o] = sv;
    }
    if (l==0){
        float lg[5], m = -1e30f;
        #pragma unroll
        for (int o=0;o<5;o++){ lg[o]=acc[o]+actb[o]; m = fmaxf(m, lg[o]); }
        float ssum=0.f;
        #pragma unroll
        for (int o=0;o<5;o++){ lg[o]=expf(lg[o]-m); ssum+=lg[o]; }
        float inv = 1.f/ssum;
        #pragma unroll
        for (int o=0;o<5;o++) store_out(out, g*5+o, lg[o]*inv);
        store_out(out, 328000 + g, acc[5] + valb[0]);
    }
}

// ---------------- node logits ----------------
__global__ __launch_bounds__(256) void k_nlog(const float* __restrict__ x,
                       const float* __restrict__ W,
                       const float* __restrict__ b, float* __restrict__ nl) {
    int n = blockIdx.x*256 + threadIdx.x;
    const float4* xr = (const float4*)(x + (size_t)n*EMB);
    float acc[5] = {b[0],b[1],b[2],b[3],b[4]};
    for (int k=0;k<32;k++){
        float4 v4 = xr[k];
        #pragma unroll
        for (int jj=0;jj<4;jj++){
            float v = (&v4.x)[jj];
            int k4 = k*4+jj;
            #pragma unroll
            for (int o=0;o<5;o++) acc[o] += v*W[k4*5+o];
        }
    }
    #pragma unroll
    for (int o=0;o<5;o++) nl[(size_t)n*5+o] = acc[o];
}

// ---------------- per-graph per-channel softmax over nodes ----------------
__global__ __launch_bounds__(256) void k_nodesm(const float* __restrict__ nl,
                         u32* __restrict__ out) {
    __shared__ float red[5][4];
    int g = blockIdx.x, t = threadIdx.x;
    float v[4][5];
    #pragma unroll
    for (int it=0; it<4; ++it){
        int n = g*NPG + it*256 + t;
        #pragma unroll
        for (int o=0;o<5;o++) v[it][o] = nl[(size_t)n*5+o];
    }
    float m[5];
    #pragma unroll
    for (int o=0;o<5;o++){
        float mm = fmaxf(fmaxf(v[0][o],v[1][o]),fmaxf(v[2][o],v[3][o]));
        #pragma unroll
        for (int d=1;d<64;d<<=1) mm = fmaxf(mm, __shfl_xor(mm,d));
        if ((t&63)==0) red[o][t>>6] = mm;
    }
    __syncthreads();
    #pragma unroll
    for (int o=0;o<5;o++)
        m[o] = fmaxf(fmaxf(red[o][0],red[o][1]),fmaxf(red[o][2],red[o][3]));
    __syncthreads();
    #pragma unroll
    for (int o=0;o<5;o++){
        float ss = 0.f;
        #pragma unroll
        for (int it=0;it<4;it++){ v[it][o] = expf(v[it][o]-m[o]); ss += v[it][o]; }
        #pragma unroll
        for (int d=1;d<64;d<<=1) ss += __shfl_xor(ss,d);
        if ((t&63)==0) red[o][t>>6] = ss;
    }
    __syncthreads();
    float s[5];
    #pragma unroll
    for (int o=0;o<5;o++)
        s[o] = 1.f/(red[o][0]+red[o][1]+red[o][2]+red[o][3]);
    #pragma unroll
    for (int it=0;it<4;it++){
        int n = g*NPG + it*256 + t;
        #pragma unroll
        for (int o=0;o<5;o++)
            store_out(out, 320 + n*5 + o, v[it][o]*s[o]);
    }
}

extern "C" void kernel_launch(void* const* d_in, const int* in_sizes, int n_in,
                              void* d_out, int out_size, void* d_ws, size_t ws_size,
                              hipStream_t stream) {
    const float* node_feats = (const float*)d_in[0];
    const float* edge_attr  = (const float*)d_in[1];
    const int*   edge_index = (const int*)d_in[2];
    const float* embed_W = (const float*)d_in[4];
    const float* embed_b = (const float*)d_in[5];
    const float* mess_W  = (const float*)d_in[6];
    const float* mess_b  = (const float*)d_in[7];
    const float* agg_W   = (const float*)d_in[8];
    const float* agg_b   = (const float*)d_in[9];
    const float* gate_W  = (const float*)d_in[10];
    const float* gate_b  = (const float*)d_in[11];
    const float* feat_W  = (const float*)d_in[12];
    const float* feat_b  = (const float*)d_in[13];
    const float* tr_W    = (const float*)d_in[14];
    const float* tr_b    = (const float*)d_in[15];
    const float* node_W  = (const float*)d_in[16];
    const float* node_b  = (const float*)d_in[17];
    const float* act_W   = (const float*)d_in[18];
    const float* act_b   = (const float*)d_in[19];
    const float* val_W   = (const float*)d_in[20];
    const float* val_b   = (const float*)d_in[21];

    char* ws = (char*)d_ws;
    float* x    = (float*)(ws);
    float* agg  = (float*)(ws + 33554432);
    float* w    = (float*)(ws + 33554432);
    float* xgn  = (float*)(ws + 33554432 + 262144);
    float* nl   = (float*)(ws + 33554432);
    u32* cnt    = (u32*)(ws + 67108864);
    u32* off    = (u32*)(ws + 67108864 + 1048576);
    u32* cursor = (u32*)(ws + 67108864 + 2097152);
    u32* perm   = (u32*)(ws + 67108864 + 3145728);
    float* xw   = (float*)(ws + 75497472);
    u32* out = (u32*)d_out;
    float* xg   = (float*)((char*)d_out + 4096);

    const int* srcv = edge_index;
    const int* dstv = edge_index + NE;

    hipMemsetAsync(cnt, 0, NTOT*sizeof(u32), stream);
    k_count  <<<NE/256, 256, 0, stream>>>(dstv, cnt);
    k_scan   <<<1, 1024, 0, stream>>>(cnt, off, cursor);
    k_scatter<<<NE/256, 256, 0, stream>>>(dstv, cursor, perm);

    hipMemsetAsync(xg, 0, NG*EMB*sizeof(float), stream);
    k_embed<<<NTOT*EMB/256, 256, 0, stream>>>(node_feats, embed_W, embed_b, x);

    for (int i=0;i<STEPS;i++){
        const float* Wm = mess_W + (size_t)i*132*EMB;
        k_xw<<<NTOT/16, 256, 0, stream>>>(x, Wm, mess_b + i*EMB, xw);
        k_msgmax2<<<NTOT/16, 256, 0, stream>>>(xw, edge_attr, srcv, off, perm,
            Wm + (size_t)128*EMB, agg);
        k_aggupd<<<NTOT/32, 256, 0, stream>>>(x, xg, agg,
            agg_W + (size_t)i*384*EMB, agg_b + i*EMB);
        k_gatepool<<<NG, 256, 0, stream>>>(x, gate_W + i*EMB, gate_b + i, w, xgn);
        k_featpool<<<NG*16, 256, 0, stream>>>(x, w,
            feat_W + (size_t)i*EMB*EMB, feat_b + i*EMB, xgn);
        k_tr<<<NG, 128, 0, stream>>>(xg, xgn, tr_W + (size_t)i*256*EMB, tr_b + i*EMB);
    }

    k_ghead<<<NG, 64, 0, stream>>>(xg, act_W, act_b, val_W, val_b, out);
    k_nlog<<<NTOT/256, 256, 0, stream>>>(x, node_W, node_b, nl);
    k_nodesm<<<NG, 256, 0, stream>>>(nl, out);
}

// Round 14
// 1006.079 us; speedup vs baseline: 11.2907x; 1.8667x over previous
//
#include <hip/hip_runtime.h>
#include <hip/hip_bf16.h>

#define NTOT  65536
#define NE    524288
#define NG    64
#define NPG   1024
#define EMB   128
#define STEPS 4

typedef unsigned short u16;
typedef unsigned int   u32;

__device__ __forceinline__ float lrelu(float v){ return v > 0.f ? v : 0.01f*v; }
__device__ __forceinline__ u16 f2bf(float f){
    u32 u = __float_as_uint(f);
    u32 r = (u + 0x7FFFu + ((u>>16)&1u)) >> 16;   // round-to-nearest-even
    return (u16)r;
}
__device__ __forceinline__ void store_out(u32* out, int j, float v){
    u32 b = (u32)f2bf(v);
    out[j] = (b << 16) | b;      // bf16 bits in both u16 halves of slot j
}

// ================= CSR build (once per launch) =================
__global__ __launch_bounds__(256) void k_count(const int* __restrict__ dstv,
                                               u32* __restrict__ cnt){
    int e = blockIdx.x*256 + threadIdx.x;
    atomicAdd(&cnt[dstv[e]], 1u);
}

__global__ __launch_bounds__(1024) void k_scan(const u32* __restrict__ cnt,
                                               u32* __restrict__ off,
                                               u32* __restrict__ cursor){
    __shared__ u32 part[1024];
    int t = threadIdx.x;
    u32 s = 0;
    for (int i=0;i<64;i++) s += cnt[t*64+i];
    part[t] = s; __syncthreads();
    for (int d=1; d<1024; d<<=1){
        u32 v = (t>=d) ? part[t-d] : 0u;
        __syncthreads();
        part[t] += v;
        __syncthreads();
    }
    u32 base = (t==0) ? 0u : part[t-1];
    for (int i=0;i<64;i++){
        off[t*64+i] = base; cursor[t*64+i] = base;
        base += cnt[t*64+i];
    }
    if (t==1023) off[65536] = base;
}

__global__ __launch_bounds__(256) void k_scatter(const int* __restrict__ dstv,
                                                 u32* __restrict__ cursor,
                                                 u32* __restrict__ perm){
    int e = blockIdx.x*256 + threadIdx.x;
    u32 pos = atomicAdd(&cursor[dstv[e]], 1u);
    perm[pos] = e;
}

// ---------------- embed: x = lrelu(nf @ W + b) ----------------
__global__ __launch_bounds__(256) void k_embed(const float* __restrict__ nf,
                        const float* __restrict__ W,
                        const float* __restrict__ b, float* __restrict__ x) {
    int idx = blockIdx.x*256 + threadIdx.x;
    int n = idx >> 7, c = idx & 127;
    const float* f = nf + n*5;
    float acc = b[c];
    #pragma unroll
    for (int k=0;k<5;k++) acc += f[k]*W[k*EMB+c];
    x[idx] = lrelu(acc);
}

// ---------------- xw = x @ W_x + b (tiled GEMM) ----------------
// tile 32 nodes x 128 cols; thread = 4 nodes x 4 cols
__global__ __launch_bounds__(256) void k_xw(const float* __restrict__ x,
                        const float* __restrict__ W,
                        const float* __restrict__ b, float* __restrict__ xw) {
    __shared__ float in[32][128];     // 16 KB
    __shared__ float Wt[32][128];     // 16 KB
    int n0 = blockIdx.x*32;
    int t = threadIdx.x;
    for (int i=t; i<32*32; i+=256){
        int ln=i>>5, kq=i&31;
        *(float4*)(&in[ln][kq*4]) = *(const float4*)(x + (size_t)(n0+ln)*EMB + kq*4);
    }
    int ng = t>>5, c = (t&31)*4;
    float4 bv = *(const float4*)(b + c);
    float4 acc0=bv, acc1=bv, acc2=bv, acc3=bv;
    for (int kt=0; kt<4; ++kt){
        __syncthreads();
        for (int i=t; i<32*32; i+=256){
            int r=i>>5, q4=i&31;
            *(float4*)(&Wt[r][q4*4]) = *(const float4*)(W + (size_t)(kt*32+r)*EMB + q4*4);
        }
        __syncthreads();
        #pragma unroll
        for (int k4=0; k4<8; ++k4){
            int kb = k4*4;
            float4 a0 = *(const float4*)(&in[ng*4+0][kt*32+kb]);
            float4 a1 = *(const float4*)(&in[ng*4+1][kt*32+kb]);
            float4 a2 = *(const float4*)(&in[ng*4+2][kt*32+kb]);
            float4 a3 = *(const float4*)(&in[ng*4+3][kt*32+kb]);
            #pragma unroll
            for (int kk=0;kk<4;kk++){
                float4 w4 = *(const float4*)(&Wt[kb+kk][c]);
                float aj;
                aj=(&a0.x)[kk]; acc0.x+=aj*w4.x; acc0.y+=aj*w4.y; acc0.z+=aj*w4.z; acc0.w+=aj*w4.w;
                aj=(&a1.x)[kk]; acc1.x+=aj*w4.x; acc1.y+=aj*w4.y; acc1.z+=aj*w4.z; acc1.w+=aj*w4.w;
                aj=(&a2.x)[kk]; acc2.x+=aj*w4.x; acc2.y+=aj*w4.y; acc2.z+=aj*w4.z; acc2.w+=aj*w4.w;
                aj=(&a3.x)[kk]; acc3.x+=aj*w4.x; acc3.y+=aj*w4.y; acc3.z+=aj*w4.z; acc3.w+=aj*w4.w;
            }
        }
    }
    float4 av[4] = {acc0,acc1,acc2,acc3};
    #pragma unroll
    for (int j=0;j<4;j++)
        *(float4*)(xw + (size_t)(n0+ng*4+j)*EMB + c) = av[j];
}

// ---------------- gather-max: agg[n] = max_e lrelu(xw[src]+ea@W_ea) ----------------
__global__ __launch_bounds__(256) void k_msgmax2(const float* __restrict__ xw,
                          const float* __restrict__ ea,
                          const int* __restrict__ srcv,
                          const u32* __restrict__ off, const u32* __restrict__ perm,
                          const float* __restrict__ Wea,
                          float* __restrict__ agg) {
    int t = threadIdx.x;
    int le = t>>4, c = (t&15)*8;
    int n = blockIdx.x*16 + le;
    float we[4][8];
    #pragma unroll
    for (int r=0;r<4;r++)
        #pragma unroll
        for (int q=0;q<8;q++) we[r][q] = Wea[r*EMB + c + q];
    u32 j0 = off[n], j1 = off[n+1];
    float racc[8];
    #pragma unroll
    for (int q=0;q<8;q++) racc[q] = -INFINITY;
    for (u32 j=j0; j<j1; ++j){
        u32 e = perm[j];
        int s = srcv[e];
        const float4 ev = *(const float4*)(ea + (size_t)e*4);
        const float4 x0 = *(const float4*)(xw + (size_t)s*EMB + c);
        const float4 x1 = *(const float4*)(xw + (size_t)s*EMB + c + 4);
        float m[8];
        m[0]=x0.x; m[1]=x0.y; m[2]=x0.z; m[3]=x0.w;
        m[4]=x1.x; m[5]=x1.y; m[6]=x1.z; m[7]=x1.w;
        #pragma unroll
        for (int q=0;q<8;q++){
            m[q] += ev.x*we[0][q] + ev.y*we[1][q] + ev.z*we[2][q] + ev.w*we[3][q];
            racc[q] = fmaxf(racc[q], lrelu(m[q]));
        }
    }
    float* o = agg + (size_t)n*EMB + c;
    #pragma unroll
    for (int q=0;q<8;q++) o[q] = (racc[q] == -INFINITY) ? 0.f : racc[q];
}

// ---------------- xgw[g] = xg[g] @ W2; also zero xgn, denom ----------------
__global__ __launch_bounds__(128) void k_xgw(const float* __restrict__ xg,
                        const float* __restrict__ W2,
                        float* __restrict__ xgw, float* __restrict__ xgn,
                        float* __restrict__ denom) {
    __shared__ float xgs[128];
    int g = blockIdx.x, t = threadIdx.x;
    xgs[t] = xg[g*EMB + t];
    __syncthreads();
    float acc = 0.f;
    for (int k=0;k<EMB;k++) acc += xgs[k]*W2[(size_t)k*EMB + t];
    xgw[g*EMB + t] = acc;
    xgn[g*EMB + t] = 0.f;
    if (t==0) denom[g] = 0.f;
}

// ---------------- x = lrelu(x@W1 + agg@W3 + xgw[g] + b) + x (tiled, K=256) ----------------
__global__ __launch_bounds__(256) void k_aggupd(float* __restrict__ x,
                         const float* __restrict__ xgw,
                         const float* __restrict__ agg,
                         const float* __restrict__ W, const float* __restrict__ b) {
    __shared__ float in[32][256];     // 32 KB  (x | agg)
    __shared__ float Wt[32][128];     // 16 KB
    int n0 = blockIdx.x*32;
    int g  = n0 >> 10;
    int t = threadIdx.x;
    for (int i=t; i<32*64; i+=256){
        int ln = i>>6, kq = i&63;
        int n = n0+ln;
        float4 v;
        if (kq < 32) v = *(const float4*)(x   + (size_t)n*EMB + kq*4);
        else         v = *(const float4*)(agg + (size_t)n*EMB + (kq-32)*4);
        *(float4*)(&in[ln][kq*4]) = v;
    }
    int ng = t>>5, c = (t&31)*4;
    float4 bv = *(const float4*)(b + c);
    float4 xv = *(const float4*)(xgw + g*EMB + c);
    bv.x += xv.x; bv.y += xv.y; bv.z += xv.z; bv.w += xv.w;
    float4 acc0=bv, acc1=bv, acc2=bv, acc3=bv;
    for (int kt=0; kt<8; ++kt){
        int wrow0 = kt*32 + ((kt>=4) ? 128 : 0);   // W1 rows [0,128), W3 rows [256,384)
        __syncthreads();
        for (int i=t; i<32*32; i+=256){
            int r=i>>5, q4=i&31;
            *(float4*)(&Wt[r][q4*4]) = *(const float4*)(W + (size_t)(wrow0+r)*EMB + q4*4);
        }
        __syncthreads();
        #pragma unroll
        for (int k4=0; k4<8; ++k4){
            int kb = k4*4;
            float4 a0 = *(const float4*)(&in[ng*4+0][kt*32+kb]);
            float4 a1 = *(const float4*)(&in[ng*4+1][kt*32+kb]);
            float4 a2 = *(const float4*)(&in[ng*4+2][kt*32+kb]);
            float4 a3 = *(const float4*)(&in[ng*4+3][kt*32+kb]);
            #pragma unroll
            for (int kk=0;kk<4;kk++){
                float4 w4 = *(const float4*)(&Wt[kb+kk][c]);
                float aj;
                aj=(&a0.x)[kk]; acc0.x+=aj*w4.x; acc0.y+=aj*w4.y; acc0.z+=aj*w4.z; acc0.w+=aj*w4.w;
                aj=(&a1.x)[kk]; acc1.x+=aj*w4.x; acc1.y+=aj*w4.y; acc1.z+=aj*w4.z; acc1.w+=aj*w4.w;
                aj=(&a2.x)[kk]; acc2.x+=aj*w4.x; acc2.y+=aj*w4.y; acc2.z+=aj*w4.z; acc2.w+=aj*w4.w;
                aj=(&a3.x)[kk]; acc3.x+=aj*w4.x; acc3.y+=aj*w4.y; acc3.z+=aj*w4.z; acc3.w+=aj*w4.w;
            }
        }
    }
    float4 av[4] = {acc0,acc1,acc2,acc3};
    #pragma unroll
    for (int j=0;j<4;j++){
        int ln = ng*4 + j;
        float* xp = x + (size_t)(n0+ln)*EMB + c;
        xp[0] = lrelu(av[j].x) + in[ln][c];
        xp[1] = lrelu(av[j].y) + in[ln][c+1];
        xp[2] = lrelu(av[j].z) + in[ln][c+2];
        xp[3] = lrelu(av[j].w) + in[ln][c+3];
    }
}

// ---------------- e[n] = exp(x[n].gw + gb); denom[g] += sum ----------------
__global__ __launch_bounds__(256) void k_gate(const float* __restrict__ x,
                           const float* __restrict__ gw,
                           const float* __restrict__ gb,
                           float* __restrict__ w, float* __restrict__ denom) {
    __shared__ float red[4];
    int t = threadIdx.x;
    int n = blockIdx.x*256 + t;
    int g = n >> 10;
    const float4* xr = (const float4*)(x + (size_t)n*EMB);
    float acc = 0.f;
    for (int k=0;k<EMB/4;k++){
        float4 v = xr[k];
        float4 g4 = ((const float4*)gw)[k];
        acc += v.x*g4.x + v.y*g4.y + v.z*g4.z + v.w*g4.w;
    }
    float e = expf(acc + gb[0]);
    w[n] = e;
    float s = e;
    #pragma unroll
    for (int o=1;o<64;o<<=1) s += __shfl_xor(s, o);
    if ((t&63)==0) red[t>>6] = s;
    __syncthreads();
    if (t==0) atomicAdd(&denom[g], red[0]+red[1]+red[2]+red[3]);
}

// ---------------- xgn[g] += sum_n e[n]*lrelu(x@fW + fb)  (tiled, unnormalized) ----------------
__global__ __launch_bounds__(256) void k_featpool(const float* __restrict__ x,
                           const float* __restrict__ w,
                           const float* __restrict__ W, const float* __restrict__ b,
                           float* __restrict__ xgn) {
    __shared__ float in[32][128];     // 16 KB
    __shared__ float Wt[32][128];     // 16 KB
    __shared__ float red[8][128];     // 4 KB
    int n0 = blockIdx.x*32;
    int g  = n0 >> 10;
    int t = threadIdx.x;
    for (int i=t; i<32*32; i+=256){
        int ln=i>>5, kq=i&31;
        *(float4*)(&in[ln][kq*4]) = *(const float4*)(x + (size_t)(n0+ln)*EMB + kq*4);
    }
    int ng = t>>5, c = (t&31)*4;
    float4 bv = *(const float4*)(b + c);
    float4 acc0=bv, acc1=bv, acc2=bv, acc3=bv;
    for (int kt=0; kt<4; ++kt){
        __syncthreads();
        for (int i=t; i<32*32; i+=256){
            int r=i>>5, q4=i&31;
            *(float4*)(&Wt[r][q4*4]) = *(const float4*)(W + (size_t)(kt*32+r)*EMB + q4*4);
        }
        __syncthreads();
        #pragma unroll
        for (int k4=0; k4<8; ++k4){
            int kb = k4*4;
            float4 a0 = *(const float4*)(&in[ng*4+0][kt*32+kb]);
            float4 a1 = *(const float4*)(&in[ng*4+1][kt*32+kb]);
            float4 a2 = *(const float4*)(&in[ng*4+2][kt*32+kb]);
            float4 a3 = *(const float4*)(&in[ng*4+3][kt*32+kb]);
            #pragma unroll
            for (int kk=0;kk<4;kk++){
                float4 w4 = *(const float4*)(&Wt[kb+kk][c]);
                float aj;
                aj=(&a0.x)[kk]; acc0.x+=aj*w4.x; acc0.y+=aj*w4.y; acc0.z+=aj*w4.z; acc0.w+=aj*w4.w;
                aj=(&a1.x)[kk]; acc1.x+=aj*w4.x; acc1.y+=aj*w4.y; acc1.z+=aj*w4.z; acc1.w+=aj*w4.w;
                aj=(&a2.x)[kk]; acc2.x+=aj*w4.x; acc2.y+=aj*w4.y; acc2.z+=aj*w4.z; acc2.w+=aj*w4.w;
                aj=(&a3.x)[kk]; acc3.x+=aj*w4.x; acc3.y+=aj*w4.y; acc3.z+=aj*w4.z; acc3.w+=aj*w4.w;
            }
        }
    }
    float wv0 = w[n0+ng*4+0], wv1 = w[n0+ng*4+1],
          wv2 = w[n0+ng*4+2], wv3 = w[n0+ng*4+3];
    float p0 = wv0*lrelu(acc0.x)+wv1*lrelu(acc1.x)+wv2*lrelu(acc2.x)+wv3*lrelu(acc3.x);
    float p1 = wv0*lrelu(acc0.y)+wv1*lrelu(acc1.y)+wv2*lrelu(acc2.y)+wv3*lrelu(acc3.y);
    float p2 = wv0*lrelu(acc0.z)+wv1*lrelu(acc1.z)+wv2*lrelu(acc2.z)+wv3*lrelu(acc3.z);
    float p3 = wv0*lrelu(acc0.w)+wv1*lrelu(acc1.w)+wv2*lrelu(acc2.w)+wv3*lrelu(acc3.w);
    __syncthreads();
    red[ng][c]=p0; red[ng][c+1]=p1; red[ng][c+2]=p2; red[ng][c+3]=p3;
    __syncthreads();
    if (t < 128){
        float s = 0.f;
        #pragma unroll
        for (int r=0;r<8;r++) s += red[r][t];
        atomicAdd(&xgn[g*EMB + t], s);
    }
}

// ---------------- xg = lrelu([xgn/denom, xg] @ W + b) + xg ----------------
__global__ __launch_bounds__(128) void k_tr(float* __restrict__ xg,
                     const float* __restrict__ xgn, const float* __restrict__ denom,
                     const float* __restrict__ W, const float* __restrict__ b) {
    __shared__ float in[256];
    int g = blockIdx.x, t = threadIdx.x;
    float inv = 1.f/denom[g];
    in[t]     = xgn[g*EMB + t]*inv;
    in[128+t] = xg[g*EMB + t];
    __syncthreads();
    float acc = b[t];
    for (int k=0;k<256;k++) acc += in[k]*W[(size_t)k*EMB + t];
    xg[g*EMB+t] = lrelu(acc) + in[128+t];
}

// ---------------- graph heads: a_probs + value ----------------
__global__ __launch_bounds__(64) void k_ghead(const float* __restrict__ xg,
                        const float* __restrict__ actW, const float* __restrict__ actb,
                        const float* __restrict__ valW, const float* __restrict__ valb,
                        u32* __restrict__ out) {
    int g = blockIdx.x, l = threadIdx.x;
    float xa = xg[g*EMB + l], xb = xg[g*EMB + 64 + l];
    float acc[6];
    #pragma unroll
    for (int o=0;o<5;o++) acc[o] = xa*actW[l*5+o] + xb*actW[(l+64)*5+o];
    acc[5] = xa*valW[l] + xb*valW[64+l];
    #pragma unroll
    for (int o=0;o<6;o++){
        float sv = acc[o];
        #pragma unroll
        for (int d=1;d<64;d<<=1) sv += __shfl_xor(sv, d);
        acc[o] = sv;
    }
    if (l==0){
        float lg[5], m = -1e30f;
        #pragma unroll
        for (int o=0;o<5;o++){ lg[o]=acc[o]+actb[o]; m = fmaxf(m, lg[o]); }
        float ssum=0.f;
        #pragma unroll
        for (int o=0;o<5;o++){ lg[o]=expf(lg[o]-m); ssum+=lg[o]; }
        float inv = 1.f/ssum;
        #pragma unroll
        for (int o=0;o<5;o++) store_out(out, g*5+o, lg[o]*inv);
        store_out(out, 328000 + g, acc[5] + valb[0]);
    }
}

// ---------------- node logits ----------------
__global__ __launch_bounds__(256) void k_nlog(const float* __restrict__ x,
                       const float* __restrict__ W,
                       const float* __restrict__ b, float* __restrict__ nl) {
    int n = blockIdx.x*256 + threadIdx.x;
    const float4* xr = (const float4*)(x + (size_t)n*EMB);
    float acc[5] = {b[0],b[1],b[2],b[3],b[4]};
    for (int k=0;k<32;k++){
        float4 v4 = xr[k];
        #pragma unroll
        for (int jj=0;jj<4;jj++){
            float v = (&v4.x)[jj];
            int k4 = k*4+jj;
            #pragma unroll
            for (int o=0;o<5;o++) acc[o] += v*W[k4*5+o];
        }
    }
    #pragma unroll
    for (int o=0;o<5;o++) nl[(size_t)n*5+o] = acc[o];
}

// ---------------- per-graph per-channel softmax over nodes ----------------
__global__ __launch_bounds__(256) void k_nodesm(const float* __restrict__ nl,
                         u32* __restrict__ out) {
    __shared__ float red[5][4];
    int g = blockIdx.x, t = threadIdx.x;
    float v[4][5];
    #pragma unroll
    for (int it=0; it<4; ++it){
        int n = g*NPG + it*256 + t;
        #pragma unroll
        for (int o=0;o<5;o++) v[it][o] = nl[(size_t)n*5+o];
    }
    float m[5];
    #pragma unroll
    for (int o=0;o<5;o++){
        float mm = fmaxf(fmaxf(v[0][o],v[1][o]),fmaxf(v[2][o],v[3][o]));
        #pragma unroll
        for (int d=1;d<64;d<<=1) mm = fmaxf(mm, __shfl_xor(mm,d));
        if ((t&63)==0) red[o][t>>6] = mm;
    }
    __syncthreads();
    #pragma unroll
    for (int o=0;o<5;o++)
        m[o] = fmaxf(fmaxf(red[o][0],red[o][1]),fmaxf(red[o][2],red[o][3]));
    __syncthreads();
    #pragma unroll
    for (int o=0;o<5;o++){
        float ss = 0.f;
        #pragma unroll
        for (int it=0;it<4;it++){ v[it][o] = expf(v[it][o]-m[o]); ss += v[it][o]; }
        #pragma unroll
        for (int d=1;d<64;d<<=1) ss += __shfl_xor(ss,d);
        if ((t&63)==0) red[o][t>>6] = ss;
    }
    __syncthreads();
    float s[5];
    #pragma unroll
    for (int o=0;o<5;o++)
        s[o] = 1.f/(red[o][0]+red[o][1]+red[o][2]+red[o][3]);
    #pragma unroll
    for (int it=0;it<4;it++){
        int n = g*NPG + it*256 + t;
        #pragma unroll
        for (int o=0;o<5;o++)
            store_out(out, 320 + n*5 + o, v[it][o]*s[o]);
    }
}

extern "C" void kernel_launch(void* const* d_in, const int* in_sizes, int n_in,
                              void* d_out, int out_size, void* d_ws, size_t ws_size,
                              hipStream_t stream) {
    const float* node_feats = (const float*)d_in[0];
    const float* edge_attr  = (const float*)d_in[1];
    const int*   edge_index = (const int*)d_in[2];
    const float* embed_W = (const float*)d_in[4];
    const float* embed_b = (const float*)d_in[5];
    const float* mess_W  = (const float*)d_in[6];
    const float* mess_b  = (const float*)d_in[7];
    const float* agg_W   = (const float*)d_in[8];
    const float* agg_b   = (const float*)d_in[9];
    const float* gate_W  = (const float*)d_in[10];
    const float* gate_b  = (const float*)d_in[11];
    const float* feat_W  = (const float*)d_in[12];
    const float* feat_b  = (const float*)d_in[13];
    const float* tr_W    = (const float*)d_in[14];
    const float* tr_b    = (const float*)d_in[15];
    const float* node_W  = (const float*)d_in[16];
    const float* node_b  = (const float*)d_in[17];
    const float* act_W   = (const float*)d_in[18];
    const float* act_b   = (const float*)d_in[19];
    const float* val_W   = (const float*)d_in[20];
    const float* val_b   = (const float*)d_in[21];

    // Workspace:
    //   x    f32 [0, 32M)
    //   agg  f32 [32M, 64M)  (w=e[], xgn, nl aliased inside, liveness-safe)
    //   CSR  [64MiB..69MiB): cnt, off, cursor, perm
    //   xgw  [70MiB) 32KB; denom [70MiB+32K) 256B
    //   xw   f32 [72MiB, 104MiB)
    char* ws = (char*)d_ws;
    float* x     = (float*)(ws);
    float* agg   = (float*)(ws + 33554432);
    float* w     = (float*)(ws + 33554432);
    float* xgn   = (float*)(ws + 33554432 + 262144);
    float* nl    = (float*)(ws + 33554432);
    u32* cnt     = (u32*)(ws + 67108864);
    u32* off     = (u32*)(ws + 67108864 + 1048576);
    u32* cursor  = (u32*)(ws + 67108864 + 2097152);
    u32* perm    = (u32*)(ws + 67108864 + 3145728);
    float* xgw   = (float*)(ws + 73400320);
    float* denom = (float*)(ws + 73400320 + 32768);
    float* xw    = (float*)(ws + 75497472);
    u32* out = (u32*)d_out;
    float* xg    = (float*)((char*)d_out + 4096);

    const int* srcv = edge_index;
    const int* dstv = edge_index + NE;

    hipMemsetAsync(cnt, 0, NTOT*sizeof(u32), stream);
    k_count  <<<NE/256, 256, 0, stream>>>(dstv, cnt);
    k_scan   <<<1, 1024, 0, stream>>>(cnt, off, cursor);
    k_scatter<<<NE/256, 256, 0, stream>>>(dstv, cursor, perm);

    hipMemsetAsync(xg, 0, NG*EMB*sizeof(float), stream);
    k_embed<<<NTOT*EMB/256, 256, 0, stream>>>(node_feats, embed_W, embed_b, x);

    for (int i=0;i<STEPS;i++){
        const float* Wm = mess_W + (size_t)i*132*EMB;
        const float* Wa = agg_W + (size_t)i*384*EMB;
        k_xw<<<NTOT/32, 256, 0, stream>>>(x, Wm, mess_b + i*EMB, xw);
        k_msgmax2<<<NTOT/16, 256, 0, stream>>>(xw, edge_attr, srcv, off, perm,
            Wm + (size_t)128*EMB, agg);
        k_xgw<<<NG, 128, 0, stream>>>(xg, Wa + (size_t)128*EMB, xgw, xgn, denom);
        k_aggupd<<<NTOT/32, 256, 0, stream>>>(x, xgw, agg, Wa, agg_b + i*EMB);
        k_gate<<<NTOT/256, 256, 0, stream>>>(x, gate_W + i*EMB, gate_b + i, w, denom);
        k_featpool<<<NTOT/32, 256, 0, stream>>>(x, w,
            feat_W + (size_t)i*EMB*EMB, feat_b + i*EMB, xgn);
        k_tr<<<NG, 128, 0, stream>>>(xg, xgn, denom, tr_W + (size_t)i*256*EMB, tr_b + i*EMB);
    }

    k_ghead<<<NG, 64, 0, stream>>>(xg, act_W, act_b, val_W, val_b, out);
    k_nlog<<<NTOT/256, 256, 0, stream>>>(x, node_W, node_b, nl);
    k_nodesm<<<NG, 256, 0, stream>>>(nl, out);
}

// Round 15
// 992.533 us; speedup vs baseline: 11.4448x; 1.0136x over previous
//
#include <hip/hip_runtime.h>
#include <hip/hip_bf16.h>

#define NTOT  65536
#define NE    524288
#define NG    64
#define NPG   1024
#define EMB   128
#define STEPS 4

typedef unsigned short u16;
typedef unsigned int   u32;

__device__ __forceinline__ float lrelu(float v){ return v > 0.f ? v : 0.01f*v; }
__device__ __forceinline__ u16 f2bf(float f){
    u32 u = __float_as_uint(f);
    u32 r = (u + 0x7FFFu + ((u>>16)&1u)) >> 16;   // round-to-nearest-even
    return (u16)r;
}
__device__ __forceinline__ void store_out(u32* out, int j, float v){
    u32 b = (u32)f2bf(v);
    out[j] = (b << 16) | b;      // bf16 bits in both u16 halves of slot j
}

// ================= CSR build (once per launch) =================
__global__ __launch_bounds__(256) void k_count(const int* __restrict__ dstv,
                                               u32* __restrict__ cnt){
    int e = blockIdx.x*256 + threadIdx.x;
    atomicAdd(&cnt[dstv[e]], 1u);
}

__global__ __launch_bounds__(1024) void k_scan(const u32* __restrict__ cnt,
                                               u32* __restrict__ off,
                                               u32* __restrict__ cursor){
    __shared__ u32 part[1024];
    int t = threadIdx.x;
    u32 s = 0;
    for (int i=0;i<64;i++) s += cnt[t*64+i];
    part[t] = s; __syncthreads();
    for (int d=1; d<1024; d<<=1){
        u32 v = (t>=d) ? part[t-d] : 0u;
        __syncthreads();
        part[t] += v;
        __syncthreads();
    }
    u32 base = (t==0) ? 0u : part[t-1];
    for (int i=0;i<64;i++){
        off[t*64+i] = base; cursor[t*64+i] = base;
        base += cnt[t*64+i];
    }
    if (t==1023) off[65536] = base;
}

__global__ __launch_bounds__(256) void k_scatter(const int* __restrict__ dstv,
                                                 u32* __restrict__ cursor,
                                                 u32* __restrict__ perm){
    int e = blockIdx.x*256 + threadIdx.x;
    u32 pos = atomicAdd(&cursor[dstv[e]], 1u);
    perm[pos] = e;
}

// ---------------- embed: x = lrelu(nf @ W + b) ----------------
__global__ __launch_bounds__(256) void k_embed(const float* __restrict__ nf,
                        const float* __restrict__ W,
                        const float* __restrict__ b, float* __restrict__ x) {
    int idx = blockIdx.x*256 + threadIdx.x;
    int n = idx >> 7, c = idx & 127;
    const float* f = nf + n*5;
    float acc = b[c];
    #pragma unroll
    for (int k=0;k<5;k++) acc += f[k]*W[k*EMB+c];
    x[idx] = lrelu(acc);
}

// ---------------- xw = x @ W_x + b (tiled GEMM; prologue only) ----------------
__global__ __launch_bounds__(256) void k_xw(const float* __restrict__ x,
                        const float* __restrict__ W,
                        const float* __restrict__ b, float* __restrict__ xw) {
    __shared__ float in[32][128];
    __shared__ float Wt[32][128];
    int n0 = blockIdx.x*32;
    int t = threadIdx.x;
    for (int i=t; i<32*32; i+=256){
        int ln=i>>5, kq=i&31;
        *(float4*)(&in[ln][kq*4]) = *(const float4*)(x + (size_t)(n0+ln)*EMB + kq*4);
    }
    int ng = t>>5, c = (t&31)*4;
    float4 bv = *(const float4*)(b + c);
    float4 acc0=bv, acc1=bv, acc2=bv, acc3=bv;
    for (int kt=0; kt<4; ++kt){
        __syncthreads();
        for (int i=t; i<32*32; i+=256){
            int r=i>>5, q4=i&31;
            *(float4*)(&Wt[r][q4*4]) = *(const float4*)(W + (size_t)(kt*32+r)*EMB + q4*4);
        }
        __syncthreads();
        #pragma unroll
        for (int k4=0; k4<8; ++k4){
            int kb = k4*4;
            float4 a0 = *(const float4*)(&in[ng*4+0][kt*32+kb]);
            float4 a1 = *(const float4*)(&in[ng*4+1][kt*32+kb]);
            float4 a2 = *(const float4*)(&in[ng*4+2][kt*32+kb]);
            float4 a3 = *(const float4*)(&in[ng*4+3][kt*32+kb]);
            #pragma unroll
            for (int kk=0;kk<4;kk++){
                float4 w4 = *(const float4*)(&Wt[kb+kk][c]);
                float aj;
                aj=(&a0.x)[kk]; acc0.x+=aj*w4.x; acc0.y+=aj*w4.y; acc0.z+=aj*w4.z; acc0.w+=aj*w4.w;
                aj=(&a1.x)[kk]; acc1.x+=aj*w4.x; acc1.y+=aj*w4.y; acc1.z+=aj*w4.z; acc1.w+=aj*w4.w;
                aj=(&a2.x)[kk]; acc2.x+=aj*w4.x; acc2.y+=aj*w4.y; acc2.z+=aj*w4.z; acc2.w+=aj*w4.w;
                aj=(&a3.x)[kk]; acc3.x+=aj*w4.x; acc3.y+=aj*w4.y; acc3.z+=aj*w4.z; acc3.w+=aj*w4.w;
            }
        }
    }
    float4 av[4] = {acc0,acc1,acc2,acc3};
    #pragma unroll
    for (int j=0;j<4;j++)
        *(float4*)(xw + (size_t)(n0+ng*4+j)*EMB + c) = av[j];
}

// ---------------- gather-max: agg[n] = max_e lrelu(xw[src]+ea@W_ea) ----------------
__global__ __launch_bounds__(256) void k_msgmax2(const float* __restrict__ xw,
                          const float* __restrict__ ea,
                          const int* __restrict__ srcv,
                          const u32* __restrict__ off, const u32* __restrict__ perm,
                          const float* __restrict__ Wea,
                          float* __restrict__ agg) {
    int t = threadIdx.x;
    int le = t>>4, c = (t&15)*8;
    int n = blockIdx.x*16 + le;
    float we[4][8];
    #pragma unroll
    for (int r=0;r<4;r++)
        #pragma unroll
        for (int q=0;q<8;q++) we[r][q] = Wea[r*EMB + c + q];
    u32 j0 = off[n], j1 = off[n+1];
    float racc[8];
    #pragma unroll
    for (int q=0;q<8;q++) racc[q] = -INFINITY;
    for (u32 j=j0; j<j1; ++j){
        u32 e = perm[j];
        int s = srcv[e];
        const float4 ev = *(const float4*)(ea + (size_t)e*4);
        const float4 x0 = *(const float4*)(xw + (size_t)s*EMB + c);
        const float4 x1 = *(const float4*)(xw + (size_t)s*EMB + c + 4);
        float m[8];
        m[0]=x0.x; m[1]=x0.y; m[2]=x0.z; m[3]=x0.w;
        m[4]=x1.x; m[5]=x1.y; m[6]=x1.z; m[7]=x1.w;
        #pragma unroll
        for (int q=0;q<8;q++){
            m[q] += ev.x*we[0][q] + ev.y*we[1][q] + ev.z*we[2][q] + ev.w*we[3][q];
            racc[q] = fmaxf(racc[q], lrelu(m[q]));
        }
    }
    float* o = agg + (size_t)n*EMB + c;
    #pragma unroll
    for (int q=0;q<8;q++) o[q] = (racc[q] == -INFINITY) ? 0.f : racc[q];
}

// ---------------- xgw[g] = xg[g] @ W2; also zero xgn, denom ----------------
__global__ __launch_bounds__(128) void k_xgw(const float* __restrict__ xg,
                        const float* __restrict__ W2,
                        float* __restrict__ xgw, float* __restrict__ xgn,
                        float* __restrict__ denom) {
    __shared__ float xgs[128];
    int g = blockIdx.x, t = threadIdx.x;
    xgs[t] = xg[g*EMB + t];
    __syncthreads();
    float acc = 0.f;
    for (int k=0;k<EMB;k++) acc += xgs[k]*W2[(size_t)k*EMB + t];
    xgw[g*EMB + t] = acc;
    xgn[g*EMB + t] = 0.f;
    if (t==0) denom[g] = 0.f;
}

// ---- FUSED: x' = lrelu(x@W1+agg@W3+xgw+b)+x ; e=exp(x'.gw+gb), denom;
//      and (if Wm) xw_next = x' @ Wm + mb ----
__global__ __launch_bounds__(256) void k_aggfused(float* __restrict__ x,
                         const float* __restrict__ xgw,
                         const float* __restrict__ agg,
                         const float* __restrict__ W, const float* __restrict__ b,
                         const float* __restrict__ gw, const float* __restrict__ gb,
                         float* __restrict__ w, float* __restrict__ denom,
                         const float* __restrict__ Wm, const float* __restrict__ mb,
                         float* __restrict__ xw) {
    __shared__ float in[32][256];     // 32 KB  (x | agg)
    __shared__ float Wt[32][128];     // 16 KB
    __shared__ float gred[8];
    int n0 = blockIdx.x*32;
    int g  = n0 >> 10;
    int t = threadIdx.x;
    for (int i=t; i<32*64; i+=256){
        int ln = i>>6, kq = i&63;
        int n = n0+ln;
        float4 v;
        if (kq < 32) v = *(const float4*)(x   + (size_t)n*EMB + kq*4);
        else         v = *(const float4*)(agg + (size_t)n*EMB + (kq-32)*4);
        *(float4*)(&in[ln][kq*4]) = v;
    }
    int ng = t>>5, c = (t&31)*4;
    float4 bv = *(const float4*)(b + c);
    float4 xv4 = *(const float4*)(xgw + g*EMB + c);
    bv.x += xv4.x; bv.y += xv4.y; bv.z += xv4.z; bv.w += xv4.w;
    float4 acc0=bv, acc1=bv, acc2=bv, acc3=bv;
    for (int kt=0; kt<8; ++kt){
        int wrow0 = kt*32 + ((kt>=4) ? 128 : 0);   // W1 rows [0,128), W3 rows [256,384)
        __syncthreads();
        for (int i=t; i<32*32; i+=256){
            int r=i>>5, q4=i&31;
            *(float4*)(&Wt[r][q4*4]) = *(const float4*)(W + (size_t)(wrow0+r)*EMB + q4*4);
        }
        __syncthreads();
        #pragma unroll
        for (int k4=0; k4<8; ++k4){
            int kb = k4*4;
            float4 a0 = *(const float4*)(&in[ng*4+0][kt*32+kb]);
            float4 a1 = *(const float4*)(&in[ng*4+1][kt*32+kb]);
            float4 a2 = *(const float4*)(&in[ng*4+2][kt*32+kb]);
            float4 a3 = *(const float4*)(&in[ng*4+3][kt*32+kb]);
            #pragma unroll
            for (int kk=0;kk<4;kk++){
                float4 w4 = *(const float4*)(&Wt[kb+kk][c]);
                float aj;
                aj=(&a0.x)[kk]; acc0.x+=aj*w4.x; acc0.y+=aj*w4.y; acc0.z+=aj*w4.z; acc0.w+=aj*w4.w;
                aj=(&a1.x)[kk]; acc1.x+=aj*w4.x; acc1.y+=aj*w4.y; acc1.z+=aj*w4.z; acc1.w+=aj*w4.w;
                aj=(&a2.x)[kk]; acc2.x+=aj*w4.x; acc2.y+=aj*w4.y; acc2.z+=aj*w4.z; acc2.w+=aj*w4.w;
                aj=(&a3.x)[kk]; acc3.x+=aj*w4.x; acc3.y+=aj*w4.y; acc3.z+=aj*w4.z; acc3.w+=aj*w4.w;
            }
        }
    }
    // epilogue: x' = lrelu(acc) + x  (keep in regs), write to global
    float4 accs[4] = {acc0,acc1,acc2,acc3};
    float xv[4][4];
    #pragma unroll
    for (int j=0;j<4;j++){
        int ln = ng*4 + j;
        #pragma unroll
        for (int kk=0;kk<4;kk++)
            xv[j][kk] = lrelu((&accs[j].x)[kk]) + in[ln][c+kk];
        *(float4*)(x + (size_t)(n0+ln)*EMB + c) =
            make_float4(xv[j][0],xv[j][1],xv[j][2],xv[j][3]);
    }
    // gate: g_n = x'. gw ; reduce over the 32 lanes of this node-group
    float4 gwv = *(const float4*)(gw + c);
    float gp[4];
    #pragma unroll
    for (int j=0;j<4;j++)
        gp[j] = xv[j][0]*gwv.x + xv[j][1]*gwv.y + xv[j][2]*gwv.z + xv[j][3]*gwv.w;
    #pragma unroll
    for (int o=1;o<32;o<<=1){
        #pragma unroll
        for (int j=0;j<4;j++) gp[j] += __shfl_xor(gp[j], o, 32);
    }
    if ((t&31)==0){
        float es = 0.f;
        #pragma unroll
        for (int j=0;j<4;j++){
            float e = expf(gp[j] + gb[0]);
            w[n0 + ng*4 + j] = e;
            es += e;
        }
        gred[ng] = es;
    }
    __syncthreads();
    if (t==0){
        float s = 0.f;
        #pragma unroll
        for (int r=0;r<8;r++) s += gred[r];
        atomicAdd(&denom[g], s);
    }
    // xw_next = x' @ Wm + mb (skip on last step)
    if (Wm){
        #pragma unroll
        for (int j=0;j<4;j++)
            *(float4*)(&in[ng*4+j][c]) =
                make_float4(xv[j][0],xv[j][1],xv[j][2],xv[j][3]);
        float4 mbv = *(const float4*)(mb + c);
        float4 bcc0=mbv, bcc1=mbv, bcc2=mbv, bcc3=mbv;
        for (int kt=0; kt<4; ++kt){
            __syncthreads();
            for (int i=t; i<32*32; i+=256){
                int r=i>>5, q4=i&31;
                *(float4*)(&Wt[r][q4*4]) = *(const float4*)(Wm + (size_t)(kt*32+r)*EMB + q4*4);
            }
            __syncthreads();
            #pragma unroll
            for (int k4=0; k4<8; ++k4){
                int kb = k4*4;
                float4 a0 = *(const float4*)(&in[ng*4+0][kt*32+kb]);
                float4 a1 = *(const float4*)(&in[ng*4+1][kt*32+kb]);
                float4 a2 = *(const float4*)(&in[ng*4+2][kt*32+kb]);
                float4 a3 = *(const float4*)(&in[ng*4+3][kt*32+kb]);
                #pragma unroll
                for (int kk=0;kk<4;kk++){
                    float4 w4 = *(const float4*)(&Wt[kb+kk][c]);
                    float aj;
                    aj=(&a0.x)[kk]; bcc0.x+=aj*w4.x; bcc0.y+=aj*w4.y; bcc0.z+=aj*w4.z; bcc0.w+=aj*w4.w;
                    aj=(&a1.x)[kk]; bcc1.x+=aj*w4.x; bcc1.y+=aj*w4.y; bcc1.z+=aj*w4.z; bcc1.w+=aj*w4.w;
                    aj=(&a2.x)[kk]; bcc2.x+=aj*w4.x; bcc2.y+=aj*w4.y; bcc2.z+=aj*w4.z; bcc2.w+=aj*w4.w;
                    aj=(&a3.x)[kk]; bcc3.x+=aj*w4.x; bcc3.y+=aj*w4.y; bcc3.z+=aj*w4.z; bcc3.w+=aj*w4.w;
                }
            }
        }
        float4 bcs[4] = {bcc0,bcc1,bcc2,bcc3};
        #pragma unroll
        for (int j=0;j<4;j++)
            *(float4*)(xw + (size_t)(n0+ng*4+j)*EMB + c) = bcs[j];
    }
}

// ---------------- xgn[g] += sum_n e[n]*lrelu(x@fW + fb)  (tiled, unnormalized) ----------------
__global__ __launch_bounds__(256) void k_featpool(const float* __restrict__ x,
                           const float* __restrict__ w,
                           const float* __restrict__ W, const float* __restrict__ b,
                           float* __restrict__ xgn) {
    __shared__ float in[32][128];
    __shared__ float Wt[32][128];
    __shared__ float red[8][128];
    int n0 = blockIdx.x*32;
    int g  = n0 >> 10;
    int t = threadIdx.x;
    for (int i=t; i<32*32; i+=256){
        int ln=i>>5, kq=i&31;
        *(float4*)(&in[ln][kq*4]) = *(const float4*)(x + (size_t)(n0+ln)*EMB + kq*4);
    }
    int ng = t>>5, c = (t&31)*4;
    float4 bv = *(const float4*)(b + c);
    float4 acc0=bv, acc1=bv, acc2=bv, acc3=bv;
    for (int kt=0; kt<4; ++kt){
        __syncthreads();
        for (int i=t; i<32*32; i+=256){
            int r=i>>5, q4=i&31;
            *(float4*)(&Wt[r][q4*4]) = *(const float4*)(W + (size_t)(kt*32+r)*EMB + q4*4);
        }
        __syncthreads();
        #pragma unroll
        for (int k4=0; k4<8; ++k4){
            int kb = k4*4;
            float4 a0 = *(const float4*)(&in[ng*4+0][kt*32+kb]);
            float4 a1 = *(const float4*)(&in[ng*4+1][kt*32+kb]);
            float4 a2 = *(const float4*)(&in[ng*4+2][kt*32+kb]);
            float4 a3 = *(const float4*)(&in[ng*4+3][kt*32+kb]);
            #pragma unroll
            for (int kk=0;kk<4;kk++){
                float4 w4 = *(const float4*)(&Wt[kb+kk][c]);
                float aj;
                aj=(&a0.x)[kk]; acc0.x+=aj*w4.x; acc0.y+=aj*w4.y; acc0.z+=aj*w4.z; acc0.w+=aj*w4.w;
                aj=(&a1.x)[kk]; acc1.x+=aj*w4.x; acc1.y+=aj*w4.y; acc1.z+=aj*w4.z; acc1.w+=aj*w4.w;
                aj=(&a2.x)[kk]; acc2.x+=aj*w4.x; acc2.y+=aj*w4.y; acc2.z+=aj*w4.z; acc2.w+=aj*w4.w;
                aj=(&a3.x)[kk]; acc3.x+=aj*w4.x; acc3.y+=aj*w4.y; acc3.z+=aj*w4.z; acc3.w+=aj*w4.w;
            }
        }
    }
    float wv0 = w[n0+ng*4+0], wv1 = w[n0+ng*4+1],
          wv2 = w[n0+ng*4+2], wv3 = w[n0+ng*4+3];
    float p0 = wv0*lrelu(acc0.x)+wv1*lrelu(acc1.x)+wv2*lrelu(acc2.x)+wv3*lrelu(acc3.x);
    float p1 = wv0*lrelu(acc0.y)+wv1*lrelu(acc1.y)+wv2*lrelu(acc2.y)+wv3*lrelu(acc3.y);
    float p2 = wv0*lrelu(acc0.z)+wv1*lrelu(acc1.z)+wv2*lrelu(acc2.z)+wv3*lrelu(acc3.z);
    float p3 = wv0*lrelu(acc0.w)+wv1*lrelu(acc1.w)+wv2*lrelu(acc2.w)+wv3*lrelu(acc3.w);
    __syncthreads();
    red[ng][c]=p0; red[ng][c+1]=p1; red[ng][c+2]=p2; red[ng][c+3]=p3;
    __syncthreads();
    if (t < 128){
        float s = 0.f;
        #pragma unroll
        for (int r=0;r<8;r++) s += red[r][t];
        atomicAdd(&xgn[g*EMB + t], s);
    }
}

// ---------------- xg = lrelu([xgn/denom, xg] @ W + b) + xg ----------------
__global__ __launch_bounds__(128) void k_tr(float* __restrict__ xg,
                     const float* __restrict__ xgn, const float* __restrict__ denom,
                     const float* __restrict__ W, const float* __restrict__ b) {
    __shared__ float in[256];
    int g = blockIdx.x, t = threadIdx.x;
    float inv = 1.f/denom[g];
    in[t]     = xgn[g*EMB + t]*inv;
    in[128+t] = xg[g*EMB + t];
    __syncthreads();
    float acc = b[t];
    for (int k=0;k<256;k++) acc += in[k]*W[(size_t)k*EMB + t];
    xg[g*EMB+t] = lrelu(acc) + in[128+t];
}

// ---------------- graph heads: a_probs + value ----------------
__global__ __launch_bounds__(64) void k_ghead(const float* __restrict__ xg,
                        const float* __restrict__ actW, const float* __restrict__ actb,
                        const float* __restrict__ valW, const float* __restrict__ valb,
                        u32* __restrict__ out) {
    int g = blockIdx.x, l = threadIdx.x;
    float xa = xg[g*EMB + l], xb = xg[g*EMB + 64 + l];
    float acc[6];
    #pragma unroll
    for (int o=0;o<5;o++) acc[o] = xa*actW[l*5+o] + xb*actW[(l+64)*5+o];
    acc[5] = xa*valW[l] + xb*valW[64+l];
    #pragma unroll
    for (int o=0;o<6;o++){
        float sv = acc[o];
        #pragma unroll
        for (int d=1;d<64;d<<=1) sv += __shfl_xor(sv, d);
        acc[o] = sv;
    }
    if (l==0){
        float lg[5], m = -1e30f;
        #pragma unroll
        for (int o=0;o<5;o++){ lg[o]=acc[o]+actb[o]; m = fmaxf(m, lg[o]); }
        float ssum=0.f;
        #pragma unroll
        for (int o=0;o<5;o++){ lg[o]=expf(lg[o]-m); ssum+=lg[o]; }
        float inv = 1.f/ssum;
        #pragma unroll
        for (int o=0;o<5;o++) store_out(out, g*5+o, lg[o]*inv);
        store_out(out, 328000 + g, acc[5] + valb[0]);
    }
}

// ---------------- node logits ----------------
__global__ __launch_bounds__(256) void k_nlog(const float* __restrict__ x,
                       const float* __restrict__ W,
                       const float* __restrict__ b, float* __restrict__ nl) {
    int n = blockIdx.x*256 + threadIdx.x;
    const float4* xr = (const float4*)(x + (size_t)n*EMB);
    float acc[5] = {b[0],b[1],b[2],b[3],b[4]};
    for (int k=0;k<32;k++){
        float4 v4 = xr[k];
        #pragma unroll
        for (int jj=0;jj<4;jj++){
            float v = (&v4.x)[jj];
            int k4 = k*4+jj;
            #pragma unroll
            for (int o=0;o<5;o++) acc[o] += v*W[k4*5+o];
        }
    }
    #pragma unroll
    for (int o=0;o<5;o++) nl[(size_t)n*5+o] = acc[o];
}

// ---------------- per-graph per-channel softmax over nodes ----------------
__global__ __launch_bounds__(256) void k_nodesm(const float* __restrict__ nl,
                         u32* __restrict__ out) {
    __shared__ float red[5][4];
    int g = blockIdx.x, t = threadIdx.x;
    float v[4][5];
    #pragma unroll
    for (int it=0; it<4; ++it){
        int n = g*NPG + it*256 + t;
        #pragma unroll
        for (int o=0;o<5;o++) v[it][o] = nl[(size_t)n*5+o];
    }
    float m[5];
    #pragma unroll
    for (int o=0;o<5;o++){
        float mm = fmaxf(fmaxf(v[0][o],v[1][o]),fmaxf(v[2][o],v[3][o]));
        #pragma unroll
        for (int d=1;d<64;d<<=1) mm = fmaxf(mm, __shfl_xor(mm,d));
        if ((t&63)==0) red[o][t>>6] = mm;
    }
    __syncthreads();
    #pragma unroll
    for (int o=0;o<5;o++)
        m[o] = fmaxf(fmaxf(red[o][0],red[o][1]),fmaxf(red[o][2],red[o][3]));
    __syncthreads();
    #pragma unroll
    for (int o=0;o<5;o++){
        float ss = 0.f;
        #pragma unroll
        for (int it=0;it<4;it++){ v[it][o] = expf(v[it][o]-m[o]); ss += v[it][o]; }
        #pragma unroll
        for (int d=1;d<64;d<<=1) ss += __shfl_xor(ss,d);
        if ((t&63)==0) red[o][t>>6] = ss;
    }
    __syncthreads();
    float s[5];
    #pragma unroll
    for (int o=0;o<5;o++)
        s[o] = 1.f/(red[o][0]+red[o][1]+red[o][2]+red[o][3]);
    #pragma unroll
    for (int it=0;it<4;it++){
        int n = g*NPG + it*256 + t;
        #pragma unroll
        for (int o=0;o<5;o++)
            store_out(out, 320 + n*5 + o, v[it][o]*s[o]);
    }
}

extern "C" void kernel_launch(void* const* d_in, const int* in_sizes, int n_in,
                              void* d_out, int out_size, void* d_ws, size_t ws_size,
                              hipStream_t stream) {
    const float* node_feats = (const float*)d_in[0];
    const float* edge_attr  = (const float*)d_in[1];
    const int*   edge_index = (const int*)d_in[2];
    const float* embed_W = (const float*)d_in[4];
    const float* embed_b = (const float*)d_in[5];
    const float* mess_W  = (const float*)d_in[6];
    const float* mess_b  = (const float*)d_in[7];
    const float* agg_W   = (const float*)d_in[8];
    const float* agg_b   = (const float*)d_in[9];
    const float* gate_W  = (const float*)d_in[10];
    const float* gate_b  = (const float*)d_in[11];
    const float* feat_W  = (const float*)d_in[12];
    const float* feat_b  = (const float*)d_in[13];
    const float* tr_W    = (const float*)d_in[14];
    const float* tr_b    = (const float*)d_in[15];
    const float* node_W  = (const float*)d_in[16];
    const float* node_b  = (const float*)d_in[17];
    const float* act_W   = (const float*)d_in[18];
    const float* act_b   = (const float*)d_in[19];
    const float* val_W   = (const float*)d_in[20];
    const float* val_b   = (const float*)d_in[21];

    char* ws = (char*)d_ws;
    float* x     = (float*)(ws);
    float* agg   = (float*)(ws + 33554432);
    float* w     = (float*)(ws + 33554432);
    float* xgn   = (float*)(ws + 33554432 + 262144);
    float* nl    = (float*)(ws + 33554432);
    u32* cnt     = (u32*)(ws + 67108864);
    u32* off     = (u32*)(ws + 67108864 + 1048576);
    u32* cursor  = (u32*)(ws + 67108864 + 2097152);
    u32* perm    = (u32*)(ws + 67108864 + 3145728);
    float* xgw   = (float*)(ws + 73400320);
    float* denom = (float*)(ws + 73400320 + 32768);
    float* xw    = (float*)(ws + 75497472);
    u32* out = (u32*)d_out;
    float* xg    = (float*)((char*)d_out + 4096);

    const int* srcv = edge_index;
    const int* dstv = edge_index + NE;

    hipMemsetAsync(cnt, 0, NTOT*sizeof(u32), stream);
    k_count  <<<NE/256, 256, 0, stream>>>(dstv, cnt);
    k_scan   <<<1, 1024, 0, stream>>>(cnt, off, cursor);
    k_scatter<<<NE/256, 256, 0, stream>>>(dstv, cursor, perm);

    hipMemsetAsync(xg, 0, NG*EMB*sizeof(float), stream);
    k_embed<<<NTOT*EMB/256, 256, 0, stream>>>(node_feats, embed_W, embed_b, x);
    k_xw<<<NTOT/32, 256, 0, stream>>>(x, mess_W, mess_b, xw);   // xw_0

    for (int i=0;i<STEPS;i++){
        const float* Wa = agg_W + (size_t)i*384*EMB;
        const float* WmN = (i+1 < STEPS) ? (mess_W + (size_t)(i+1)*132*EMB) : nullptr;
        const float* mbN = (i+1 < STEPS) ? (mess_b + (i+1)*EMB) : nullptr;
        k_msgmax2<<<NTOT/16, 256, 0, stream>>>(xw, edge_attr, srcv, off, perm,
            mess_W + (size_t)i*132*EMB + (size_t)128*EMB, agg);
        k_xgw<<<NG, 128, 0, stream>>>(xg, Wa + (size_t)128*EMB, xgw, xgn, denom);
        k_aggfused<<<NTOT/32, 256, 0, stream>>>(x, xgw, agg, Wa, agg_b + i*EMB,
            gate_W + i*EMB, gate_b + i, w, denom, WmN, mbN, xw);
        k_featpool<<<NTOT/32, 256, 0, stream>>>(x, w,
            feat_W + (size_t)i*EMB*EMB, feat_b + i*EMB, xgn);
        k_tr<<<NG, 128, 0, stream>>>(xg, xgn, denom, tr_W + (size_t)i*256*EMB, tr_b + i*EMB);
    }

    k_ghead<<<NG, 64, 0, stream>>>(xg, act_W, act_b, val_W, val_b, out);
    k_nlog<<<NTOT/256, 256, 0, stream>>>(x, node_W, node_b, nl);
    k_nodesm<<<NG, 256, 0, stream>>>(nl, out);
}